// Round 1
// baseline (477.363 us; speedup 1.0000x reference)
//
#include <hip/hip_runtime.h>

// 2-layer single-head GATConv, fp32, on MI355X.
// N=50000 nodes, E=800000 edges, IN=128, HID=64, OUT=32.
//
// Softmax over incoming edges is shift-invariant -> skip segment_max.
// Per layer: (A) per-edge exp(leaky_relu(ls[src]+ld[dst])) + atomic denom[dst]
//            (B) per-edge alpha*h[src] atomically added into acc[dst]
// Biases are preloaded into the accumulators by k_init (no + b epilogue pass).

#define N_NODES 50000
#define N_EDGES 800000
#define SLOPE 0.2f

static __device__ __forceinline__ void atomicAddF(float* p, float v) {
    __hip_atomic_fetch_add(p, v, __ATOMIC_RELAXED, __HIP_MEMORY_SCOPE_AGENT);
}

// ---------------------------------------------------------------------------
// init: acc1[n][c] = b1[c]; out[n][c] = b2[c]; denom1/denom2 = 0
__global__ __launch_bounds__(256) void k_init(
    const float* __restrict__ b1, const float* __restrict__ b2,
    float* __restrict__ acc1, float* __restrict__ dout,
    float* __restrict__ denom1, float* __restrict__ denom2)
{
    int i = blockIdx.x * 256 + threadIdx.x;
    if (i < N_NODES * 64) acc1[i] = b1[i & 63];
    if (i < N_NODES * 32) dout[i] = b2[i & 31];
    if (i < N_NODES) { denom1[i] = 0.f; denom2[i] = 0.f; }
}

// ---------------------------------------------------------------------------
// GEMM1: h1 = x @ W1  (50000x128 @ 128x64), fused ls1 = h1.a_src, ld1 = h1.a_dst
// Block: 256 threads = 16x16, tile 64 rows x 64 cols, K=128 in one LDS tile.
__global__ __launch_bounds__(256) void k_gemm1(
    const float* __restrict__ x, const float* __restrict__ W1,
    const float* __restrict__ a_src, const float* __restrict__ a_dst,
    float* __restrict__ h1, float* __restrict__ ls, float* __restrict__ ld)
{
    __shared__ float As[64][128];   // 32 KB
    __shared__ float Bs[128][64];   // 32 KB
    const int tid = threadIdx.x;
    const int m0 = blockIdx.x * 64;

    {   // W1 (128x64 = 2048 float4) -> Bs
        const float4* Wv = (const float4*)W1;
        float4* Bv = (float4*)&Bs[0][0];
        #pragma unroll
        for (int i = 0; i < 8; ++i) Bv[tid + i * 256] = Wv[tid + i * 256];
    }
    {   // x tile (64x128) -> As, coalesced float4, zero-pad past N
        const float4* Xv = (const float4*)x;
        #pragma unroll
        for (int i = 0; i < 8; ++i) {
            int idx = tid + i * 256;
            int r = idx >> 5, kq = idx & 31;        // 32 float4 per row
            float4 v = make_float4(0.f, 0.f, 0.f, 0.f);
            if (m0 + r < N_NODES) v = Xv[(size_t)(m0 + r) * 32 + kq];
            ((float4*)&As[r][0])[kq] = v;
        }
    }
    __syncthreads();

    const int tx = tid & 15, ty = tid >> 4;
    const int c0 = tx * 4, r0 = ty * 4;
    float acc[4][4] = {};
    for (int k = 0; k < 128; k += 4) {
        float a_s[4][4];
        #pragma unroll
        for (int i = 0; i < 4; ++i) {
            float4 av = *(const float4*)&As[r0 + i][k];
            a_s[i][0] = av.x; a_s[i][1] = av.y; a_s[i][2] = av.z; a_s[i][3] = av.w;
        }
        #pragma unroll
        for (int kk = 0; kk < 4; ++kk) {
            float4 b = *(const float4*)&Bs[k + kk][c0];
            #pragma unroll
            for (int i = 0; i < 4; ++i) {
                acc[i][0] += a_s[i][kk] * b.x;
                acc[i][1] += a_s[i][kk] * b.y;
                acc[i][2] += a_s[i][kk] * b.z;
                acc[i][3] += a_s[i][kk] * b.w;
            }
        }
    }

    // attention score vectors (broadcast, L1-cached)
    float as4[4], ad4[4];
    #pragma unroll
    for (int j = 0; j < 4; ++j) { as4[j] = a_src[c0 + j]; ad4[j] = a_dst[c0 + j]; }

    #pragma unroll
    for (int i = 0; i < 4; ++i) {
        int row = m0 + r0 + i;
        float pls = acc[i][0]*as4[0] + acc[i][1]*as4[1] + acc[i][2]*as4[2] + acc[i][3]*as4[3];
        float pld = acc[i][0]*ad4[0] + acc[i][1]*ad4[1] + acc[i][2]*ad4[2] + acc[i][3]*ad4[3];
        // reduce across the 16 tx lanes (lane = ty*16+tx, xor bits 0..3 stay in-group)
        #pragma unroll
        for (int off = 1; off < 16; off <<= 1) {
            pls += __shfl_xor(pls, off, 64);
            pld += __shfl_xor(pld, off, 64);
        }
        if (row < N_NODES) {
            ((float4*)&h1[(size_t)row * 64])[tx] =
                make_float4(acc[i][0], acc[i][1], acc[i][2], acc[i][3]);
            if (tx == 0) { ls[row] = pls; ld[row] = pld; }
        }
    }
}

// ---------------------------------------------------------------------------
// Pass A: ew[e] = exp(leaky_relu(ls[src]+ld[dst])); denom[dst] += ew[e]
__global__ __launch_bounds__(256) void k_edge_a(
    const int* __restrict__ src, const int* __restrict__ dst,
    const float* __restrict__ ls, const float* __restrict__ ld,
    float* __restrict__ ew, float* __restrict__ denom)
{
    int e = blockIdx.x * 256 + threadIdx.x;
    if (e >= N_EDGES) return;
    int s = src[e], d = dst[e];
    float l = ls[s] + ld[d];
    l = l > 0.f ? l : SLOPE * l;
    float w = __expf(l);
    ew[e] = w;
    atomicAddF(&denom[d], w);
}

// ---------------------------------------------------------------------------
// Pass B, layer 1 (C=64): one wave per edge, lane = channel.
__global__ __launch_bounds__(256) void k_edge_b1(
    const int* __restrict__ src, const int* __restrict__ dst,
    const float* __restrict__ ew, const float* __restrict__ denom,
    const float* __restrict__ h1, float* __restrict__ acc1)
{
    int e = blockIdx.x * 4 + (threadIdx.x >> 6);   // grid*4 == N_EDGES exactly
    int lane = threadIdx.x & 63;
    int s = src[e], d = dst[e];
    float alpha = ew[e] / denom[d];
    atomicAddF(&acc1[(size_t)d * 64 + lane], alpha * h1[(size_t)s * 64 + lane]);
}

// ---------------------------------------------------------------------------
// Epilogue layer1 + GEMM2: h2 = relu(acc1) @ W2, fused ls2/ld2.
// Block handles 64 nodes; bias b1 was preloaded into acc1 by k_init.
__global__ __launch_bounds__(256) void k_epi1(
    const float* __restrict__ acc1, const float* __restrict__ W2,
    const float* __restrict__ a_src2, const float* __restrict__ a_dst2,
    float* __restrict__ h2, float* __restrict__ ls2, float* __restrict__ ld2)
{
    __shared__ float Hs[64][68];   // +4 pad, keeps float4 alignment, breaks conflicts
    __shared__ float W2s[64][32];  // 8 KB
    const int tid = threadIdx.x;
    const int n0 = blockIdx.x * 64;

    {   // W2 (64x32 = 512 float4) -> LDS
        const float4* Wv = (const float4*)W2;
        float4* Ws = (float4*)&W2s[0][0];
        Ws[tid] = Wv[tid];
        Ws[tid + 256] = Wv[tid + 256];
    }
    {   // relu(acc1 rows) -> Hs, coalesced
        const float4* Av = (const float4*)acc1;
        #pragma unroll
        for (int i = 0; i < 4; ++i) {
            int idx = tid + i * 256;
            int r = idx >> 4, kq = idx & 15;       // 16 float4 per row
            float4 v = make_float4(0.f, 0.f, 0.f, 0.f);
            if (n0 + r < N_NODES) {
                v = Av[(size_t)(n0 + r) * 16 + kq];
                v.x = fmaxf(v.x, 0.f); v.y = fmaxf(v.y, 0.f);
                v.z = fmaxf(v.z, 0.f); v.w = fmaxf(v.w, 0.f);
            }
            ((float4*)&Hs[r][0])[kq] = v;
        }
    }
    __syncthreads();

    const int nl = tid >> 2, cg = tid & 3, c0 = cg * 8;
    float acc[8] = {};
    for (int k4 = 0; k4 < 16; ++k4) {
        float4 hv4 = *(const float4*)&Hs[nl][k4 * 4];
        #pragma unroll
        for (int kk = 0; kk < 4; ++kk) {
            float hv = kk == 0 ? hv4.x : kk == 1 ? hv4.y : kk == 2 ? hv4.z : hv4.w;
            int k = k4 * 4 + kk;
            float4 w0 = *(const float4*)&W2s[k][c0];
            float4 w1 = *(const float4*)&W2s[k][c0 + 4];
            acc[0] += hv * w0.x; acc[1] += hv * w0.y;
            acc[2] += hv * w0.z; acc[3] += hv * w0.w;
            acc[4] += hv * w1.x; acc[5] += hv * w1.y;
            acc[6] += hv * w1.z; acc[7] += hv * w1.w;
        }
    }

    float pls = 0.f, pld = 0.f;
    #pragma unroll
    for (int j = 0; j < 8; ++j) {
        pls += acc[j] * a_src2[c0 + j];
        pld += acc[j] * a_dst2[c0 + j];
    }
    // reduce across the 4 cg lanes (consecutive lanes share a node)
    pls += __shfl_xor(pls, 1, 64); pls += __shfl_xor(pls, 2, 64);
    pld += __shfl_xor(pld, 1, 64); pld += __shfl_xor(pld, 2, 64);

    int node = n0 + nl;
    if (node < N_NODES) {
        ((float4*)&h2[(size_t)node * 32])[cg * 2] =
            make_float4(acc[0], acc[1], acc[2], acc[3]);
        ((float4*)&h2[(size_t)node * 32])[cg * 2 + 1] =
            make_float4(acc[4], acc[5], acc[6], acc[7]);
        if (cg == 0) { ls2[node] = pls; ld2[node] = pld; }
    }
}

// ---------------------------------------------------------------------------
// Pass B, layer 2 (C=32): half-wave per edge.
__global__ __launch_bounds__(256) void k_edge_b2(
    const int* __restrict__ src, const int* __restrict__ dst,
    const float* __restrict__ ew, const float* __restrict__ denom,
    const float* __restrict__ h2, float* __restrict__ dout)
{
    int idx = blockIdx.x * 256 + threadIdx.x;   // grid*8 == N_EDGES exactly
    int e = idx >> 5, c = idx & 31;
    int s = src[e], d = dst[e];
    float alpha = ew[e] / denom[d];
    atomicAddF(&dout[(size_t)d * 32 + c], alpha * h2[(size_t)s * 32 + c]);
}

// ---------------------------------------------------------------------------
extern "C" void kernel_launch(void* const* d_in, const int* in_sizes, int n_in,
                              void* d_out, int out_size, void* d_ws, size_t ws_size,
                              hipStream_t stream)
{
    const float* x      = (const float*)d_in[0];
    const int*   ei     = (const int*)  d_in[1];
    const float* W1     = (const float*)d_in[2];
    const float* a_src1 = (const float*)d_in[3];
    const float* a_dst1 = (const float*)d_in[4];
    // b1 = d_in[5]
    const float* W2     = (const float*)d_in[6];
    const float* a_src2 = (const float*)d_in[7];
    const float* a_dst2 = (const float*)d_in[8];
    // b2 = d_in[9]
    const float* b1 = (const float*)d_in[5];
    const float* b2 = (const float*)d_in[9];
    const int* src = ei;
    const int* dst = ei + N_EDGES;
    float* out = (float*)d_out;

    // workspace layout (floats); h2 aliases dead h1, ew2 aliases dead ew1.
    // total 7.5M floats = 30 MB.
    float* ws     = (float*)d_ws;
    float* h1     = ws;                 // 3.2M
    float* acc1   = ws + 3200000;       // 3.2M
    float* ew     = ws + 6400000;       // 800k
    float* ls1    = ws + 7200000;       // 50k
    float* ld1    = ws + 7250000;
    float* ls2    = ws + 7300000;
    float* ld2    = ws + 7350000;
    float* denom1 = ws + 7400000;
    float* denom2 = ws + 7450000;
    float* h2     = h1;

    k_init   <<<12500, 256, 0, stream>>>(b1, b2, acc1, out, denom1, denom2);
    k_gemm1  <<<782,   256, 0, stream>>>(x, W1, a_src1, a_dst1, h1, ls1, ld1);
    k_edge_a <<<3125,  256, 0, stream>>>(src, dst, ls1, ld1, ew, denom1);
    k_edge_b1<<<200000,256, 0, stream>>>(src, dst, ew, denom1, h1, acc1);
    k_epi1   <<<782,   256, 0, stream>>>(acc1, W2, a_src2, a_dst2, h2, ls2, ld2);
    k_edge_a <<<3125,  256, 0, stream>>>(src, dst, ls2, ld2, ew, denom2);
    k_edge_b2<<<100000,256, 0, stream>>>(src, dst, ew, denom2, h2, out);
}

// Round 2
// 391.302 us; speedup vs baseline: 1.2199x; 1.2199x over previous
//
#include <hip/hip_runtime.h>

// 2-layer single-head GATConv, fp32, MI355X.
// N=50000 nodes, E=800000 edges, IN=128, HID=64, OUT=32.
//
// Round 1 -> 2: replaced all float-atomic scatter passes with a counting-sort
// CSR (sorted by dst, built once, reused by both layers) + per-node gather
// aggregation. Softmax is a ratio: out[d] = b + (sum_e w_e*h[src_e]) / (sum_e w_e),
// so numerator and denominator accumulate in ONE pass; no ew/denom arrays,
// no segment_max (shift-invariance; logits are O(10), no overflow risk).

#define N_NODES 50000
#define N_EDGES 800000
#define SLOPE 0.2f

// ---------------------------------------------------------------------------
// counts[i] = 0
__global__ __launch_bounds__(256) void k_zero(int* __restrict__ counts)
{
    int i = blockIdx.x * 256 + threadIdx.x;
    if (i < N_NODES) counts[i] = 0;
}

// histogram of dst
__global__ __launch_bounds__(256) void k_hist(
    const int* __restrict__ dst, int* __restrict__ counts)
{
    int e = blockIdx.x * 256 + threadIdx.x;
    if (e < N_EDGES) atomicAdd(&counts[dst[e]], 1);
}

// single-block exclusive scan of counts -> row_start[N+1], cursor[]
// (cursor may alias counts: each element is read-then-written by one thread)
#define SCAN_CHUNK 49
__global__ __launch_bounds__(1024) void k_scan(
    const int* counts, int* row_start, int* cursor)
{
    __shared__ int part[1024];
    const int t = threadIdx.x;
    const int beg = t * SCAN_CHUNK;
    const int end = min(beg + SCAN_CHUNK, N_NODES);
    int s = 0;
    for (int i = beg; i < end; ++i) s += counts[i];
    part[t] = s;
    __syncthreads();
    for (int off = 1; off < 1024; off <<= 1) {
        int v = (t >= off) ? part[t - off] : 0;
        __syncthreads();
        part[t] += v;
        __syncthreads();
    }
    int run = part[t] - s;          // exclusive prefix of this chunk
    for (int i = beg; i < end; ++i) {
        int c = counts[i];
        row_start[i] = run;
        cursor[i] = run;
        run += c;
    }
    if (t == 1023) row_start[N_NODES] = run;   // == N_EDGES
}

// scatter src ids into dst-sorted order
__global__ __launch_bounds__(256) void k_scatter(
    const int* __restrict__ src, const int* __restrict__ dst,
    int* cursor, int* __restrict__ csr_src)
{
    int e = blockIdx.x * 256 + threadIdx.x;
    if (e >= N_EDGES) return;
    int d = dst[e];
    int p = atomicAdd(&cursor[d], 1);
    csr_src[p] = src[e];
}

// ---------------------------------------------------------------------------
// GEMM1: h1 = x @ W1  (50000x128 @ 128x64), fused ls1 = h1.a_src, ld1 = h1.a_dst
__global__ __launch_bounds__(256) void k_gemm1(
    const float* __restrict__ x, const float* __restrict__ W1,
    const float* __restrict__ a_src, const float* __restrict__ a_dst,
    float* __restrict__ h1, float* __restrict__ ls, float* __restrict__ ld)
{
    __shared__ float As[64][128];   // 32 KB
    __shared__ float Bs[128][64];   // 32 KB
    const int tid = threadIdx.x;
    const int m0 = blockIdx.x * 64;

    {   // W1 (128x64 = 2048 float4) -> Bs
        const float4* Wv = (const float4*)W1;
        float4* Bv = (float4*)&Bs[0][0];
        #pragma unroll
        for (int i = 0; i < 8; ++i) Bv[tid + i * 256] = Wv[tid + i * 256];
    }
    {   // x tile (64x128) -> As, coalesced float4, zero-pad past N
        const float4* Xv = (const float4*)x;
        #pragma unroll
        for (int i = 0; i < 8; ++i) {
            int idx = tid + i * 256;
            int r = idx >> 5, kq = idx & 31;        // 32 float4 per row
            float4 v = make_float4(0.f, 0.f, 0.f, 0.f);
            if (m0 + r < N_NODES) v = Xv[(size_t)(m0 + r) * 32 + kq];
            ((float4*)&As[r][0])[kq] = v;
        }
    }
    __syncthreads();

    const int tx = tid & 15, ty = tid >> 4;
    const int c0 = tx * 4, r0 = ty * 4;
    float acc[4][4] = {};
    for (int k = 0; k < 128; k += 4) {
        float a_s[4][4];
        #pragma unroll
        for (int i = 0; i < 4; ++i) {
            float4 av = *(const float4*)&As[r0 + i][k];
            a_s[i][0] = av.x; a_s[i][1] = av.y; a_s[i][2] = av.z; a_s[i][3] = av.w;
        }
        #pragma unroll
        for (int kk = 0; kk < 4; ++kk) {
            float4 b = *(const float4*)&Bs[k + kk][c0];
            #pragma unroll
            for (int i = 0; i < 4; ++i) {
                acc[i][0] += a_s[i][kk] * b.x;
                acc[i][1] += a_s[i][kk] * b.y;
                acc[i][2] += a_s[i][kk] * b.z;
                acc[i][3] += a_s[i][kk] * b.w;
            }
        }
    }

    float as4[4], ad4[4];
    #pragma unroll
    for (int j = 0; j < 4; ++j) { as4[j] = a_src[c0 + j]; ad4[j] = a_dst[c0 + j]; }

    #pragma unroll
    for (int i = 0; i < 4; ++i) {
        int row = m0 + r0 + i;
        float pls = acc[i][0]*as4[0] + acc[i][1]*as4[1] + acc[i][2]*as4[2] + acc[i][3]*as4[3];
        float pld = acc[i][0]*ad4[0] + acc[i][1]*ad4[1] + acc[i][2]*ad4[2] + acc[i][3]*ad4[3];
        #pragma unroll
        for (int off = 1; off < 16; off <<= 1) {
            pls += __shfl_xor(pls, off, 64);
            pld += __shfl_xor(pld, off, 64);
        }
        if (row < N_NODES) {
            ((float4*)&h1[(size_t)row * 64])[tx] =
                make_float4(acc[i][0], acc[i][1], acc[i][2], acc[i][3]);
            if (tx == 0) { ls[row] = pls; ld[row] = pld; }
        }
    }
}

// ---------------------------------------------------------------------------
// Aggregate layer 1 (C=64): one wave per dst node, lane = channel.
// acc1[d] = b1 + (sum_e w_e * h1[src_e]) / (sum_e w_e)
__global__ __launch_bounds__(256) void k_agg1(
    const int* __restrict__ csr_src, const int* __restrict__ row_start,
    const float* __restrict__ ls, const float* __restrict__ ld,
    const float* __restrict__ h1, const float* __restrict__ b1,
    float* __restrict__ acc1)
{
    const int node = blockIdx.x * 4 + (threadIdx.x >> 6);  // 12500*4 == N_NODES
    const int lane = threadIdx.x & 63;
    const int beg = row_start[node], end = row_start[node + 1];
    const float ldv = ld[node];

    float sw0 = 0.f, swh0 = 0.f, sw1 = 0.f, swh1 = 0.f;
    int j = beg;
    for (; j + 2 <= end; j += 2) {
        int s0 = csr_src[j], s1 = csr_src[j + 1];
        float hv0 = h1[(size_t)s0 * 64 + lane];
        float hv1 = h1[(size_t)s1 * 64 + lane];
        float l0 = ls[s0] + ldv, l1 = ls[s1] + ldv;
        l0 = l0 > 0.f ? l0 : SLOPE * l0;
        l1 = l1 > 0.f ? l1 : SLOPE * l1;
        float w0 = __expf(l0), w1 = __expf(l1);
        sw0 += w0; swh0 += w0 * hv0;
        sw1 += w1; swh1 += w1 * hv1;
    }
    if (j < end) {
        int s0 = csr_src[j];
        float hv0 = h1[(size_t)s0 * 64 + lane];
        float l0 = ls[s0] + ldv;
        l0 = l0 > 0.f ? l0 : SLOPE * l0;
        float w0 = __expf(l0);
        sw0 += w0; swh0 += w0 * hv0;
    }
    float sw = sw0 + sw1, swh = swh0 + swh1;
    float r = sw > 0.f ? swh / sw : 0.f;
    acc1[(size_t)node * 64 + lane] = r + b1[lane];
}

// ---------------------------------------------------------------------------
// Epilogue layer1 + GEMM2: h2 = relu(acc1) @ W2, fused ls2/ld2.
__global__ __launch_bounds__(256) void k_epi1(
    const float* __restrict__ acc1, const float* __restrict__ W2,
    const float* __restrict__ a_src2, const float* __restrict__ a_dst2,
    float* __restrict__ h2, float* __restrict__ ls2, float* __restrict__ ld2)
{
    __shared__ float Hs[64][68];
    __shared__ float W2s[64][32];
    const int tid = threadIdx.x;
    const int n0 = blockIdx.x * 64;

    {   // W2 (64x32 = 512 float4) -> LDS
        const float4* Wv = (const float4*)W2;
        float4* Ws = (float4*)&W2s[0][0];
        Ws[tid] = Wv[tid];
        Ws[tid + 256] = Wv[tid + 256];
    }
    {   // relu(acc1 rows) -> Hs, coalesced
        const float4* Av = (const float4*)acc1;
        #pragma unroll
        for (int i = 0; i < 4; ++i) {
            int idx = tid + i * 256;
            int r = idx >> 4, kq = idx & 15;
            float4 v = make_float4(0.f, 0.f, 0.f, 0.f);
            if (n0 + r < N_NODES) {
                v = Av[(size_t)(n0 + r) * 16 + kq];
                v.x = fmaxf(v.x, 0.f); v.y = fmaxf(v.y, 0.f);
                v.z = fmaxf(v.z, 0.f); v.w = fmaxf(v.w, 0.f);
            }
            ((float4*)&Hs[r][0])[kq] = v;
        }
    }
    __syncthreads();

    const int nl = tid >> 2, cg = tid & 3, c0 = cg * 8;
    float acc[8] = {};
    for (int k4 = 0; k4 < 16; ++k4) {
        float4 hv4 = *(const float4*)&Hs[nl][k4 * 4];
        #pragma unroll
        for (int kk = 0; kk < 4; ++kk) {
            float hv = kk == 0 ? hv4.x : kk == 1 ? hv4.y : kk == 2 ? hv4.z : hv4.w;
            int k = k4 * 4 + kk;
            float4 w0 = *(const float4*)&W2s[k][c0];
            float4 w1 = *(const float4*)&W2s[k][c0 + 4];
            acc[0] += hv * w0.x; acc[1] += hv * w0.y;
            acc[2] += hv * w0.z; acc[3] += hv * w0.w;
            acc[4] += hv * w1.x; acc[5] += hv * w1.y;
            acc[6] += hv * w1.z; acc[7] += hv * w1.w;
        }
    }

    float pls = 0.f, pld = 0.f;
    #pragma unroll
    for (int j = 0; j < 8; ++j) {
        pls += acc[j] * a_src2[c0 + j];
        pld += acc[j] * a_dst2[c0 + j];
    }
    pls += __shfl_xor(pls, 1, 64); pls += __shfl_xor(pls, 2, 64);
    pld += __shfl_xor(pld, 1, 64); pld += __shfl_xor(pld, 2, 64);

    int node = n0 + nl;
    if (node < N_NODES) {
        ((float4*)&h2[(size_t)node * 32])[cg * 2] =
            make_float4(acc[0], acc[1], acc[2], acc[3]);
        ((float4*)&h2[(size_t)node * 32])[cg * 2 + 1] =
            make_float4(acc[4], acc[5], acc[6], acc[7]);
        if (cg == 0) { ls2[node] = pls; ld2[node] = pld; }
    }
}

// ---------------------------------------------------------------------------
// Aggregate layer 2 (C=32): half-wave per dst node. Writes final output.
__global__ __launch_bounds__(256) void k_agg2(
    const int* __restrict__ csr_src, const int* __restrict__ row_start,
    const float* __restrict__ ls, const float* __restrict__ ld,
    const float* __restrict__ h2, const float* __restrict__ b2,
    float* __restrict__ out)
{
    const int idx = blockIdx.x * 256 + threadIdx.x;   // 6250*256 == N*32
    const int node = idx >> 5;
    const int c = idx & 31;
    const int beg = row_start[node], end = row_start[node + 1];
    const float ldv = ld[node];

    float sw0 = 0.f, swh0 = 0.f, sw1 = 0.f, swh1 = 0.f;
    int j = beg;
    for (; j + 2 <= end; j += 2) {
        int s0 = csr_src[j], s1 = csr_src[j + 1];
        float hv0 = h2[(size_t)s0 * 32 + c];
        float hv1 = h2[(size_t)s1 * 32 + c];
        float l0 = ls[s0] + ldv, l1 = ls[s1] + ldv;
        l0 = l0 > 0.f ? l0 : SLOPE * l0;
        l1 = l1 > 0.f ? l1 : SLOPE * l1;
        float w0 = __expf(l0), w1 = __expf(l1);
        sw0 += w0; swh0 += w0 * hv0;
        sw1 += w1; swh1 += w1 * hv1;
    }
    if (j < end) {
        int s0 = csr_src[j];
        float hv0 = h2[(size_t)s0 * 32 + c];
        float l0 = ls[s0] + ldv;
        l0 = l0 > 0.f ? l0 : SLOPE * l0;
        float w0 = __expf(l0);
        sw0 += w0; swh0 += w0 * hv0;
    }
    float sw = sw0 + sw1, swh = swh0 + swh1;
    float r = sw > 0.f ? swh / sw : 0.f;
    out[(size_t)node * 32 + c] = r + b2[c];
}

// ---------------------------------------------------------------------------
extern "C" void kernel_launch(void* const* d_in, const int* in_sizes, int n_in,
                              void* d_out, int out_size, void* d_ws, size_t ws_size,
                              hipStream_t stream)
{
    const float* x      = (const float*)d_in[0];
    const int*   ei     = (const int*)  d_in[1];
    const float* W1     = (const float*)d_in[2];
    const float* a_src1 = (const float*)d_in[3];
    const float* a_dst1 = (const float*)d_in[4];
    const float* b1     = (const float*)d_in[5];
    const float* W2     = (const float*)d_in[6];
    const float* a_src2 = (const float*)d_in[7];
    const float* a_dst2 = (const float*)d_in[8];
    const float* b2     = (const float*)d_in[9];
    const int* src = ei;
    const int* dst = ei + N_EDGES;
    float* out = (float*)d_out;

    // workspace (words): total 7,400,016 < 7.5M (29.6 MB)
    float* ws   = (float*)d_ws;
    float* h1   = ws;                       // 3,200,000 f (h2 aliases after agg1)
    float* acc1 = ws + 3200000;             // 3,200,000 f
    float* ls1  = ws + 6400000;             // 50,000 f (ls2 aliases after agg1)
    float* ld1  = ws + 6450000;             // 50,000 f (ld2 aliases after agg1)
    int* row_start = (int*)(ws + 6500000);  // 50,001 i (padded to 50,016)
    int* counts    = (int*)(ws + 6550016);  // 50,000 i (cursor aliases counts)
    int* csr_src   = (int*)(ws + 6600016);  // 800,000 i
    float* h2  = h1;
    float* ls2 = ls1;
    float* ld2 = ld1;
    int* cursor = counts;

    // CSR build (reused by both layers)
    k_zero   <<<196,  256, 0, stream>>>(counts);
    k_hist   <<<3125, 256, 0, stream>>>(dst, counts);
    k_scan   <<<1,   1024, 0, stream>>>(counts, row_start, cursor);
    k_scatter<<<3125, 256, 0, stream>>>(src, dst, cursor, csr_src);

    // layer 1
    k_gemm1<<<782,   256, 0, stream>>>(x, W1, a_src1, a_dst1, h1, ls1, ld1);
    k_agg1 <<<12500, 256, 0, stream>>>(csr_src, row_start, ls1, ld1, h1, b1, acc1);

    // layer 2
    k_epi1 <<<782,  256, 0, stream>>>(acc1, W2, a_src2, a_dst2, h2, ls2, ld2);
    k_agg2 <<<6250, 256, 0, stream>>>(csr_src, row_start, ls2, ld2, h2, b2, out);
}

// Round 3
// 295.742 us; speedup vs baseline: 1.6141x; 1.3231x over previous
//
#include <hip/hip_runtime.h>

// 2-layer single-head GATConv, fp32, MI355X.
// N=50000 nodes, E=800000 edges, IN=128, HID=64, OUT=32.
//
// Round 2 -> 3: the single-block k_scan was 111us (one CU, 255 idle).
// Replaced with a 3-stage device-wide scan (block-scan -> scan block sums ->
// add offsets). Everything else unchanged: counting-sort CSR by dst, then
// per-node one-pass softmax aggregation (ratio form, no segment_max needed).

#define N_NODES 50000
#define N_EDGES 800000
#define SLOPE 0.2f

// ---------------------------------------------------------------------------
__global__ __launch_bounds__(256) void k_zero(int* __restrict__ counts)
{
    int i = blockIdx.x * 256 + threadIdx.x;
    if (i < N_NODES) counts[i] = 0;
}

__global__ __launch_bounds__(256) void k_hist(
    const int* __restrict__ dst, int* __restrict__ counts)
{
    int e = blockIdx.x * 256 + threadIdx.x;
    if (e < N_EDGES) atomicAdd(&counts[dst[e]], 1);
}

// stage 1: per-block (256-wide) scan; pre[i] = exclusive prefix within block,
// blocksum[b] = block total.
__global__ __launch_bounds__(256) void k_scan1(
    const int* __restrict__ counts, int* __restrict__ pre,
    int* __restrict__ blocksum)
{
    __shared__ int tmp[256];
    const int t = threadIdx.x;
    const int i = blockIdx.x * 256 + t;
    int v = (i < N_NODES) ? counts[i] : 0;
    tmp[t] = v;
    __syncthreads();
    #pragma unroll
    for (int off = 1; off < 256; off <<= 1) {
        int u = (t >= off) ? tmp[t - off] : 0;
        __syncthreads();
        tmp[t] += u;
        __syncthreads();
    }
    if (i < N_NODES) pre[i] = tmp[t] - v;
    if (t == 255) blocksum[blockIdx.x] = tmp[255];
}

// stage 2: exclusive scan of the 196 block sums (one block).
__global__ __launch_bounds__(256) void k_scan2(int* __restrict__ blocksum)
{
    __shared__ int tmp[256];
    const int t = threadIdx.x;
    int v = (t < 196) ? blocksum[t] : 0;
    tmp[t] = v;
    __syncthreads();
    #pragma unroll
    for (int off = 1; off < 256; off <<= 1) {
        int u = (t >= off) ? tmp[t - off] : 0;
        __syncthreads();
        tmp[t] += u;
        __syncthreads();
    }
    if (t < 196) blocksum[t] = tmp[t] - v;
}

// stage 3: row_start[i] = cursor[i] = pre[i] + blocksum[block]; sentinel.
__global__ __launch_bounds__(256) void k_scan3(
    const int* __restrict__ pre, const int* __restrict__ blocksum,
    int* __restrict__ row_start, int* __restrict__ cursor)
{
    const int i = blockIdx.x * 256 + threadIdx.x;
    if (i < N_NODES) {
        int r = pre[i] + blocksum[blockIdx.x];
        row_start[i] = r;
        cursor[i] = r;
    }
    if (i == 0) row_start[N_NODES] = N_EDGES;
}

__global__ __launch_bounds__(256) void k_scatter(
    const int* __restrict__ src, const int* __restrict__ dst,
    int* cursor, int* __restrict__ csr_src)
{
    int e = blockIdx.x * 256 + threadIdx.x;
    if (e >= N_EDGES) return;
    int d = dst[e];
    int p = atomicAdd(&cursor[d], 1);
    csr_src[p] = src[e];
}

// ---------------------------------------------------------------------------
// GEMM1: h1 = x @ W1  (50000x128 @ 128x64), fused ls1 = h1.a_src, ld1 = h1.a_dst
__global__ __launch_bounds__(256) void k_gemm1(
    const float* __restrict__ x, const float* __restrict__ W1,
    const float* __restrict__ a_src, const float* __restrict__ a_dst,
    float* __restrict__ h1, float* __restrict__ ls, float* __restrict__ ld)
{
    __shared__ float As[64][128];   // 32 KB
    __shared__ float Bs[128][64];   // 32 KB
    const int tid = threadIdx.x;
    const int m0 = blockIdx.x * 64;

    {   // W1 (128x64 = 2048 float4) -> Bs
        const float4* Wv = (const float4*)W1;
        float4* Bv = (float4*)&Bs[0][0];
        #pragma unroll
        for (int i = 0; i < 8; ++i) Bv[tid + i * 256] = Wv[tid + i * 256];
    }
    {   // x tile (64x128) -> As, coalesced float4, zero-pad past N
        const float4* Xv = (const float4*)x;
        #pragma unroll
        for (int i = 0; i < 8; ++i) {
            int idx = tid + i * 256;
            int r = idx >> 5, kq = idx & 31;        // 32 float4 per row
            float4 v = make_float4(0.f, 0.f, 0.f, 0.f);
            if (m0 + r < N_NODES) v = Xv[(size_t)(m0 + r) * 32 + kq];
            ((float4*)&As[r][0])[kq] = v;
        }
    }
    __syncthreads();

    const int tx = tid & 15, ty = tid >> 4;
    const int c0 = tx * 4, r0 = ty * 4;
    float acc[4][4] = {};
    for (int k = 0; k < 128; k += 4) {
        float a_s[4][4];
        #pragma unroll
        for (int i = 0; i < 4; ++i) {
            float4 av = *(const float4*)&As[r0 + i][k];
            a_s[i][0] = av.x; a_s[i][1] = av.y; a_s[i][2] = av.z; a_s[i][3] = av.w;
        }
        #pragma unroll
        for (int kk = 0; kk < 4; ++kk) {
            float4 b = *(const float4*)&Bs[k + kk][c0];
            #pragma unroll
            for (int i = 0; i < 4; ++i) {
                acc[i][0] += a_s[i][kk] * b.x;
                acc[i][1] += a_s[i][kk] * b.y;
                acc[i][2] += a_s[i][kk] * b.z;
                acc[i][3] += a_s[i][kk] * b.w;
            }
        }
    }

    float as4[4], ad4[4];
    #pragma unroll
    for (int j = 0; j < 4; ++j) { as4[j] = a_src[c0 + j]; ad4[j] = a_dst[c0 + j]; }

    #pragma unroll
    for (int i = 0; i < 4; ++i) {
        int row = m0 + r0 + i;
        float pls = acc[i][0]*as4[0] + acc[i][1]*as4[1] + acc[i][2]*as4[2] + acc[i][3]*as4[3];
        float pld = acc[i][0]*ad4[0] + acc[i][1]*ad4[1] + acc[i][2]*ad4[2] + acc[i][3]*ad4[3];
        #pragma unroll
        for (int off = 1; off < 16; off <<= 1) {
            pls += __shfl_xor(pls, off, 64);
            pld += __shfl_xor(pld, off, 64);
        }
        if (row < N_NODES) {
            ((float4*)&h1[(size_t)row * 64])[tx] =
                make_float4(acc[i][0], acc[i][1], acc[i][2], acc[i][3]);
            if (tx == 0) { ls[row] = pls; ld[row] = pld; }
        }
    }
}

// ---------------------------------------------------------------------------
// Aggregate layer 1 (C=64): one wave per dst node, lane = channel.
__global__ __launch_bounds__(256) void k_agg1(
    const int* __restrict__ csr_src, const int* __restrict__ row_start,
    const float* __restrict__ ls, const float* __restrict__ ld,
    const float* __restrict__ h1, const float* __restrict__ b1,
    float* __restrict__ acc1)
{
    const int node = blockIdx.x * 4 + (threadIdx.x >> 6);  // 12500*4 == N_NODES
    const int lane = threadIdx.x & 63;
    const int beg = row_start[node], end = row_start[node + 1];
    const float ldv = ld[node];

    float sw0 = 0.f, swh0 = 0.f, sw1 = 0.f, swh1 = 0.f;
    int j = beg;
    for (; j + 2 <= end; j += 2) {
        int s0 = csr_src[j], s1 = csr_src[j + 1];
        float hv0 = h1[(size_t)s0 * 64 + lane];
        float hv1 = h1[(size_t)s1 * 64 + lane];
        float l0 = ls[s0] + ldv, l1 = ls[s1] + ldv;
        l0 = l0 > 0.f ? l0 : SLOPE * l0;
        l1 = l1 > 0.f ? l1 : SLOPE * l1;
        float w0 = __expf(l0), w1 = __expf(l1);
        sw0 += w0; swh0 += w0 * hv0;
        sw1 += w1; swh1 += w1 * hv1;
    }
    if (j < end) {
        int s0 = csr_src[j];
        float hv0 = h1[(size_t)s0 * 64 + lane];
        float l0 = ls[s0] + ldv;
        l0 = l0 > 0.f ? l0 : SLOPE * l0;
        float w0 = __expf(l0);
        sw0 += w0; swh0 += w0 * hv0;
    }
    float sw = sw0 + sw1, swh = swh0 + swh1;
    float r = sw > 0.f ? swh / sw : 0.f;
    acc1[(size_t)node * 64 + lane] = r + b1[lane];
}

// ---------------------------------------------------------------------------
// Epilogue layer1 + GEMM2: h2 = relu(acc1) @ W2, fused ls2/ld2.
__global__ __launch_bounds__(256) void k_epi1(
    const float* __restrict__ acc1, const float* __restrict__ W2,
    const float* __restrict__ a_src2, const float* __restrict__ a_dst2,
    float* __restrict__ h2, float* __restrict__ ls2, float* __restrict__ ld2)
{
    __shared__ float Hs[64][68];
    __shared__ float W2s[64][32];
    const int tid = threadIdx.x;
    const int n0 = blockIdx.x * 64;

    {   // W2 (64x32 = 512 float4) -> LDS
        const float4* Wv = (const float4*)W2;
        float4* Ws = (float4*)&W2s[0][0];
        Ws[tid] = Wv[tid];
        Ws[tid + 256] = Wv[tid + 256];
    }
    {   // relu(acc1 rows) -> Hs, coalesced
        const float4* Av = (const float4*)acc1;
        #pragma unroll
        for (int i = 0; i < 4; ++i) {
            int idx = tid + i * 256;
            int r = idx >> 4, kq = idx & 15;
            float4 v = make_float4(0.f, 0.f, 0.f, 0.f);
            if (n0 + r < N_NODES) {
                v = Av[(size_t)(n0 + r) * 16 + kq];
                v.x = fmaxf(v.x, 0.f); v.y = fmaxf(v.y, 0.f);
                v.z = fmaxf(v.z, 0.f); v.w = fmaxf(v.w, 0.f);
            }
            ((float4*)&Hs[r][0])[kq] = v;
        }
    }
    __syncthreads();

    const int nl = tid >> 2, cg = tid & 3, c0 = cg * 8;
    float acc[8] = {};
    for (int k4 = 0; k4 < 16; ++k4) {
        float4 hv4 = *(const float4*)&Hs[nl][k4 * 4];
        #pragma unroll
        for (int kk = 0; kk < 4; ++kk) {
            float hv = kk == 0 ? hv4.x : kk == 1 ? hv4.y : kk == 2 ? hv4.z : hv4.w;
            int k = k4 * 4 + kk;
            float4 w0 = *(const float4*)&W2s[k][c0];
            float4 w1 = *(const float4*)&W2s[k][c0 + 4];
            acc[0] += hv * w0.x; acc[1] += hv * w0.y;
            acc[2] += hv * w0.z; acc[3] += hv * w0.w;
            acc[4] += hv * w1.x; acc[5] += hv * w1.y;
            acc[6] += hv * w1.z; acc[7] += hv * w1.w;
        }
    }

    float pls = 0.f, pld = 0.f;
    #pragma unroll
    for (int j = 0; j < 8; ++j) {
        pls += acc[j] * a_src2[c0 + j];
        pld += acc[j] * a_dst2[c0 + j];
    }
    pls += __shfl_xor(pls, 1, 64); pls += __shfl_xor(pls, 2, 64);
    pld += __shfl_xor(pld, 1, 64); pld += __shfl_xor(pld, 2, 64);

    int node = n0 + nl;
    if (node < N_NODES) {
        ((float4*)&h2[(size_t)node * 32])[cg * 2] =
            make_float4(acc[0], acc[1], acc[2], acc[3]);
        ((float4*)&h2[(size_t)node * 32])[cg * 2 + 1] =
            make_float4(acc[4], acc[5], acc[6], acc[7]);
        if (cg == 0) { ls2[node] = pls; ld2[node] = pld; }
    }
}

// ---------------------------------------------------------------------------
// Aggregate layer 2 (C=32): half-wave per dst node. Writes final output.
__global__ __launch_bounds__(256) void k_agg2(
    const int* __restrict__ csr_src, const int* __restrict__ row_start,
    const float* __restrict__ ls, const float* __restrict__ ld,
    const float* __restrict__ h2, const float* __restrict__ b2,
    float* __restrict__ out)
{
    const int idx = blockIdx.x * 256 + threadIdx.x;   // 6250*256 == N*32
    const int node = idx >> 5;
    const int c = idx & 31;
    const int beg = row_start[node], end = row_start[node + 1];
    const float ldv = ld[node];

    float sw0 = 0.f, swh0 = 0.f, sw1 = 0.f, swh1 = 0.f;
    int j = beg;
    for (; j + 2 <= end; j += 2) {
        int s0 = csr_src[j], s1 = csr_src[j + 1];
        float hv0 = h2[(size_t)s0 * 32 + c];
        float hv1 = h2[(size_t)s1 * 32 + c];
        float l0 = ls[s0] + ldv, l1 = ls[s1] + ldv;
        l0 = l0 > 0.f ? l0 : SLOPE * l0;
        l1 = l1 > 0.f ? l1 : SLOPE * l1;
        float w0 = __expf(l0), w1 = __expf(l1);
        sw0 += w0; swh0 += w0 * hv0;
        sw1 += w1; swh1 += w1 * hv1;
    }
    if (j < end) {
        int s0 = csr_src[j];
        float hv0 = h2[(size_t)s0 * 32 + c];
        float l0 = ls[s0] + ldv;
        l0 = l0 > 0.f ? l0 : SLOPE * l0;
        float w0 = __expf(l0);
        sw0 += w0; swh0 += w0 * hv0;
    }
    float sw = sw0 + sw1, swh = swh0 + swh1;
    float r = sw > 0.f ? swh / sw : 0.f;
    out[(size_t)node * 32 + c] = r + b2[c];
}

// ---------------------------------------------------------------------------
extern "C" void kernel_launch(void* const* d_in, const int* in_sizes, int n_in,
                              void* d_out, int out_size, void* d_ws, size_t ws_size,
                              hipStream_t stream)
{
    const float* x      = (const float*)d_in[0];
    const int*   ei     = (const int*)  d_in[1];
    const float* W1     = (const float*)d_in[2];
    const float* a_src1 = (const float*)d_in[3];
    const float* a_dst1 = (const float*)d_in[4];
    const float* b1     = (const float*)d_in[5];
    const float* W2     = (const float*)d_in[6];
    const float* a_src2 = (const float*)d_in[7];
    const float* a_dst2 = (const float*)d_in[8];
    const float* b2     = (const float*)d_in[9];
    const int* src = ei;
    const int* dst = ei + N_EDGES;
    float* out = (float*)d_out;

    // workspace (words): total 7,450,272 < ws (29.8 MB)
    float* ws   = (float*)d_ws;
    float* h1   = ws;                       // 3,200,000 f (h2 aliases)
    float* acc1 = ws + 3200000;             // 3,200,000 f
    float* ls1  = ws + 6400000;             // 50,000 f (ls2 aliases)
    float* ld1  = ws + 6450000;             // 50,000 f (ld2 aliases)
    int* row_start = (int*)(ws + 6500000);  // 50,001 i (pad to 50,016)
    int* counts    = (int*)(ws + 6550016);  // 50,000 i (cursor aliases)
    int* csr_src   = (int*)(ws + 6600016);  // 800,000 i
    int* pre       = (int*)(ws + 7400016);  // 50,000 i
    int* blocksum  = (int*)(ws + 7450016);  // 196 i
    float* h2  = h1;
    float* ls2 = ls1;
    float* ld2 = ld1;
    int* cursor = counts;

    // CSR build (reused by both layers)
    k_zero   <<<196,  256, 0, stream>>>(counts);
    k_hist   <<<3125, 256, 0, stream>>>(dst, counts);
    k_scan1  <<<196,  256, 0, stream>>>(counts, pre, blocksum);
    k_scan2  <<<1,    256, 0, stream>>>(blocksum);
    k_scan3  <<<196,  256, 0, stream>>>(pre, blocksum, row_start, cursor);
    k_scatter<<<3125, 256, 0, stream>>>(src, dst, cursor, csr_src);

    // layer 1
    k_gemm1<<<782,   256, 0, stream>>>(x, W1, a_src1, a_dst1, h1, ls1, ld1);
    k_agg1 <<<12500, 256, 0, stream>>>(csr_src, row_start, ls1, ld1, h1, b1, acc1);

    // layer 2
    k_epi1 <<<782,  256, 0, stream>>>(acc1, W2, a_src2, a_dst2, h2, ls2, ld2);
    k_agg2 <<<6250, 256, 0, stream>>>(csr_src, row_start, ls2, ld2, h2, b2, out);
}

// Round 4
// 227.190 us; speedup vs baseline: 2.1012x; 1.3017x over previous
//
#include <hip/hip_runtime.h>

// 2-layer single-head GATConv, fp32, MI355X.
// N=50000 nodes, E=800000 edges, IN=128, HID=64, OUT=32.
//
// Round 3 -> 4: k_scatter (random 4B writes, 64B-line x 8-XCD write
// amplification -> 52 MB WRITE_SIZE, 54us) replaced by a two-level bucket
// sort: k_bin stages (src,dst) pairs into 196 dst-buckets with block-local
// LDS ranking (line-dense writes), k_sort gives each bucket to one block
// which counting-sorts 256 dst nodes in LDS and writes a contiguous csr_src
// slice + row_start directly. k_zero/k_hist/k_scan1-3 are deleted (per-dst
// counts now come from k_sort's LDS histogram).

#define N_NODES 50000
#define N_EDGES 800000
#define SLOPE 0.2f
#define NBUCK 196           // ceil(50000/256) buckets of 256 dst nodes
#define CAP 4608            // staging capacity per bucket (mean 4096, sigma 64)

// ---------------------------------------------------------------------------
__global__ __launch_bounds__(256) void k_zerobins(int* __restrict__ binctr)
{
    if (threadIdx.x < NBUCK) binctr[threadIdx.x] = 0;
}

// Stage edges into per-bucket regions. 98 blocks x 1024 thr x 8 edges.
__global__ __launch_bounds__(1024) void k_bin(
    const int* __restrict__ src, const int* __restrict__ dst,
    int* __restrict__ binctr,
    int* __restrict__ stg_src, int* __restrict__ stg_dst)
{
    __shared__ int hist[NBUCK];
    __shared__ int gb[NBUCK];
    const int t = threadIdx.x;
    if (t < NBUCK) hist[t] = 0;
    __syncthreads();

    const int base = blockIdx.x * 8192;
    int ms[8], md[8], mr[8];
    int n = 0;
    #pragma unroll
    for (int k = 0; k < 8; ++k) {
        int e = base + t + k * 1024;
        if (e < N_EDGES) {
            int s = src[e], d = dst[e];
            ms[n] = s; md[n] = d;
            mr[n] = atomicAdd(&hist[d >> 8], 1);   // rank within block-bucket
            ++n;
        }
    }
    __syncthreads();
    if (t < NBUCK) gb[t] = atomicAdd(&binctr[t], hist[t]);  // reserve range
    __syncthreads();
    for (int i = 0; i < n; ++i) {
        int b = md[i] >> 8;
        int p = b * CAP + gb[b] + mr[i];
        stg_src[p] = ms[i];
        stg_dst[p] = md[i];
    }
}

// Exclusive scan of 196 bucket counts -> bucket_base.
__global__ __launch_bounds__(256) void k_btot(
    const int* __restrict__ binctr, int* __restrict__ bucket_base)
{
    __shared__ int tmp[256];
    const int t = threadIdx.x;
    int v = (t < NBUCK) ? binctr[t] : 0;
    tmp[t] = v;
    __syncthreads();
    #pragma unroll
    for (int off = 1; off < 256; off <<= 1) {
        int u = (t >= off) ? tmp[t - off] : 0;
        __syncthreads();
        tmp[t] += u;
        __syncthreads();
    }
    if (t < NBUCK) bucket_base[t] = tmp[t] - v;
}

// One block per bucket: counting-sort its 256 dst nodes in LDS, write
// contiguous csr_src slice + row_start for its nodes.
__global__ __launch_bounds__(1024) void k_sort(
    const int* __restrict__ stg_src, const int* __restrict__ stg_dst,
    const int* __restrict__ binctr, const int* __restrict__ bucket_base,
    int* __restrict__ row_start, int* __restrict__ csr_src)
{
    __shared__ int cnt[256];
    __shared__ int off[256];
    const int b = blockIdx.x, t = threadIdx.x;
    const int n = binctr[b];
    const int sbase = b * CAP;
    const int obase = bucket_base[b];

    if (t < 256) cnt[t] = 0;
    __syncthreads();

    int ms[5], mk[5], mr[5];
    int c = 0;
    for (int i = t; i < n; i += 1024) {
        int s = stg_src[sbase + i], d = stg_dst[sbase + i];
        int k = d & 255;
        ms[c] = s; mk[c] = k;
        mr[c] = atomicAdd(&cnt[k], 1);
        ++c;
    }
    __syncthreads();

    if (t < 256) off[t] = cnt[t];
    __syncthreads();
    #pragma unroll
    for (int o = 1; o < 256; o <<= 1) {
        int u = (t < 256 && t >= o) ? off[t - o] : 0;
        __syncthreads();
        if (t < 256) off[t] += u;
        __syncthreads();
    }
    // off = inclusive scan; exclusive prefix = off[k] - cnt[k]

    if (t < 256) {
        int node = b * 256 + t;
        if (node < N_NODES) row_start[node] = obase + off[t] - cnt[t];
    }
    if (b == NBUCK - 1 && t == 0) row_start[N_NODES] = N_EDGES;

    for (int i = 0; i < c; ++i)
        csr_src[obase + off[mk[i]] - cnt[mk[i]] + mr[i]] = ms[i];
}

// ---------------------------------------------------------------------------
// GEMM1: h1 = x @ W1  (50000x128 @ 128x64), fused ls1 = h1.a_src, ld1 = h1.a_dst
__global__ __launch_bounds__(256) void k_gemm1(
    const float* __restrict__ x, const float* __restrict__ W1,
    const float* __restrict__ a_src, const float* __restrict__ a_dst,
    float* __restrict__ h1, float* __restrict__ ls, float* __restrict__ ld)
{
    __shared__ float As[64][128];   // 32 KB
    __shared__ float Bs[128][64];   // 32 KB
    const int tid = threadIdx.x;
    const int m0 = blockIdx.x * 64;

    {   // W1 (128x64 = 2048 float4) -> Bs
        const float4* Wv = (const float4*)W1;
        float4* Bv = (float4*)&Bs[0][0];
        #pragma unroll
        for (int i = 0; i < 8; ++i) Bv[tid + i * 256] = Wv[tid + i * 256];
    }
    {   // x tile (64x128) -> As, coalesced float4, zero-pad past N
        const float4* Xv = (const float4*)x;
        #pragma unroll
        for (int i = 0; i < 8; ++i) {
            int idx = tid + i * 256;
            int r = idx >> 5, kq = idx & 31;        // 32 float4 per row
            float4 v = make_float4(0.f, 0.f, 0.f, 0.f);
            if (m0 + r < N_NODES) v = Xv[(size_t)(m0 + r) * 32 + kq];
            ((float4*)&As[r][0])[kq] = v;
        }
    }
    __syncthreads();

    const int tx = tid & 15, ty = tid >> 4;
    const int c0 = tx * 4, r0 = ty * 4;
    float acc[4][4] = {};
    for (int k = 0; k < 128; k += 4) {
        float a_s[4][4];
        #pragma unroll
        for (int i = 0; i < 4; ++i) {
            float4 av = *(const float4*)&As[r0 + i][k];
            a_s[i][0] = av.x; a_s[i][1] = av.y; a_s[i][2] = av.z; a_s[i][3] = av.w;
        }
        #pragma unroll
        for (int kk = 0; kk < 4; ++kk) {
            float4 b = *(const float4*)&Bs[k + kk][c0];
            #pragma unroll
            for (int i = 0; i < 4; ++i) {
                acc[i][0] += a_s[i][kk] * b.x;
                acc[i][1] += a_s[i][kk] * b.y;
                acc[i][2] += a_s[i][kk] * b.z;
                acc[i][3] += a_s[i][kk] * b.w;
            }
        }
    }

    float as4[4], ad4[4];
    #pragma unroll
    for (int j = 0; j < 4; ++j) { as4[j] = a_src[c0 + j]; ad4[j] = a_dst[c0 + j]; }

    #pragma unroll
    for (int i = 0; i < 4; ++i) {
        int row = m0 + r0 + i;
        float pls = acc[i][0]*as4[0] + acc[i][1]*as4[1] + acc[i][2]*as4[2] + acc[i][3]*as4[3];
        float pld = acc[i][0]*ad4[0] + acc[i][1]*ad4[1] + acc[i][2]*ad4[2] + acc[i][3]*ad4[3];
        #pragma unroll
        for (int off = 1; off < 16; off <<= 1) {
            pls += __shfl_xor(pls, off, 64);
            pld += __shfl_xor(pld, off, 64);
        }
        if (row < N_NODES) {
            ((float4*)&h1[(size_t)row * 64])[tx] =
                make_float4(acc[i][0], acc[i][1], acc[i][2], acc[i][3]);
            if (tx == 0) { ls[row] = pls; ld[row] = pld; }
        }
    }
}

// ---------------------------------------------------------------------------
// Aggregate layer 1 (C=64): one wave per dst node, lane = channel.
__global__ __launch_bounds__(256) void k_agg1(
    const int* __restrict__ csr_src, const int* __restrict__ row_start,
    const float* __restrict__ ls, const float* __restrict__ ld,
    const float* __restrict__ h1, const float* __restrict__ b1,
    float* __restrict__ acc1)
{
    const int node = blockIdx.x * 4 + (threadIdx.x >> 6);  // 12500*4 == N_NODES
    const int lane = threadIdx.x & 63;
    const int beg = row_start[node], end = row_start[node + 1];
    const float ldv = ld[node];

    float sw0 = 0.f, swh0 = 0.f, sw1 = 0.f, swh1 = 0.f;
    int j = beg;
    for (; j + 2 <= end; j += 2) {
        int s0 = csr_src[j], s1 = csr_src[j + 1];
        float hv0 = h1[(size_t)s0 * 64 + lane];
        float hv1 = h1[(size_t)s1 * 64 + lane];
        float l0 = ls[s0] + ldv, l1 = ls[s1] + ldv;
        l0 = l0 > 0.f ? l0 : SLOPE * l0;
        l1 = l1 > 0.f ? l1 : SLOPE * l1;
        float w0 = __expf(l0), w1 = __expf(l1);
        sw0 += w0; swh0 += w0 * hv0;
        sw1 += w1; swh1 += w1 * hv1;
    }
    if (j < end) {
        int s0 = csr_src[j];
        float hv0 = h1[(size_t)s0 * 64 + lane];
        float l0 = ls[s0] + ldv;
        l0 = l0 > 0.f ? l0 : SLOPE * l0;
        float w0 = __expf(l0);
        sw0 += w0; swh0 += w0 * hv0;
    }
    float sw = sw0 + sw1, swh = swh0 + swh1;
    float r = sw > 0.f ? swh / sw : 0.f;
    acc1[(size_t)node * 64 + lane] = r + b1[lane];
}

// ---------------------------------------------------------------------------
// Epilogue layer1 + GEMM2: h2 = relu(acc1) @ W2, fused ls2/ld2.
__global__ __launch_bounds__(256) void k_epi1(
    const float* __restrict__ acc1, const float* __restrict__ W2,
    const float* __restrict__ a_src2, const float* __restrict__ a_dst2,
    float* __restrict__ h2, float* __restrict__ ls2, float* __restrict__ ld2)
{
    __shared__ float Hs[64][68];
    __shared__ float W2s[64][32];
    const int tid = threadIdx.x;
    const int n0 = blockIdx.x * 64;

    {   // W2 (64x32 = 512 float4) -> LDS
        const float4* Wv = (const float4*)W2;
        float4* Ws = (float4*)&W2s[0][0];
        Ws[tid] = Wv[tid];
        Ws[tid + 256] = Wv[tid + 256];
    }
    {   // relu(acc1 rows) -> Hs, coalesced
        const float4* Av = (const float4*)acc1;
        #pragma unroll
        for (int i = 0; i < 4; ++i) {
            int idx = tid + i * 256;
            int r = idx >> 4, kq = idx & 15;
            float4 v = make_float4(0.f, 0.f, 0.f, 0.f);
            if (n0 + r < N_NODES) {
                v = Av[(size_t)(n0 + r) * 16 + kq];
                v.x = fmaxf(v.x, 0.f); v.y = fmaxf(v.y, 0.f);
                v.z = fmaxf(v.z, 0.f); v.w = fmaxf(v.w, 0.f);
            }
            ((float4*)&Hs[r][0])[kq] = v;
        }
    }
    __syncthreads();

    const int nl = tid >> 2, cg = tid & 3, c0 = cg * 8;
    float acc[8] = {};
    for (int k4 = 0; k4 < 16; ++k4) {
        float4 hv4 = *(const float4*)&Hs[nl][k4 * 4];
        #pragma unroll
        for (int kk = 0; kk < 4; ++kk) {
            float hv = kk == 0 ? hv4.x : kk == 1 ? hv4.y : kk == 2 ? hv4.z : hv4.w;
            int k = k4 * 4 + kk;
            float4 w0 = *(const float4*)&W2s[k][c0];
            float4 w1 = *(const float4*)&W2s[k][c0 + 4];
            acc[0] += hv * w0.x; acc[1] += hv * w0.y;
            acc[2] += hv * w0.z; acc[3] += hv * w0.w;
            acc[4] += hv * w1.x; acc[5] += hv * w1.y;
            acc[6] += hv * w1.z; acc[7] += hv * w1.w;
        }
    }

    float pls = 0.f, pld = 0.f;
    #pragma unroll
    for (int j = 0; j < 8; ++j) {
        pls += acc[j] * a_src2[c0 + j];
        pld += acc[j] * a_dst2[c0 + j];
    }
    pls += __shfl_xor(pls, 1, 64); pls += __shfl_xor(pls, 2, 64);
    pld += __shfl_xor(pld, 1, 64); pld += __shfl_xor(pld, 2, 64);

    int node = n0 + nl;
    if (node < N_NODES) {
        ((float4*)&h2[(size_t)node * 32])[cg * 2] =
            make_float4(acc[0], acc[1], acc[2], acc[3]);
        ((float4*)&h2[(size_t)node * 32])[cg * 2 + 1] =
            make_float4(acc[4], acc[5], acc[6], acc[7]);
        if (cg == 0) { ls2[node] = pls; ld2[node] = pld; }
    }
}

// ---------------------------------------------------------------------------
// Aggregate layer 2 (C=32): half-wave per dst node. Writes final output.
__global__ __launch_bounds__(256) void k_agg2(
    const int* __restrict__ csr_src, const int* __restrict__ row_start,
    const float* __restrict__ ls, const float* __restrict__ ld,
    const float* __restrict__ h2, const float* __restrict__ b2,
    float* __restrict__ out)
{
    const int idx = blockIdx.x * 256 + threadIdx.x;   // 6250*256 == N*32
    const int node = idx >> 5;
    const int c = idx & 31;
    const int beg = row_start[node], end = row_start[node + 1];
    const float ldv = ld[node];

    float sw0 = 0.f, swh0 = 0.f, sw1 = 0.f, swh1 = 0.f;
    int j = beg;
    for (; j + 2 <= end; j += 2) {
        int s0 = csr_src[j], s1 = csr_src[j + 1];
        float hv0 = h2[(size_t)s0 * 32 + c];
        float hv1 = h2[(size_t)s1 * 32 + c];
        float l0 = ls[s0] + ldv, l1 = ls[s1] + ldv;
        l0 = l0 > 0.f ? l0 : SLOPE * l0;
        l1 = l1 > 0.f ? l1 : SLOPE * l1;
        float w0 = __expf(l0), w1 = __expf(l1);
        sw0 += w0; swh0 += w0 * hv0;
        sw1 += w1; swh1 += w1 * hv1;
    }
    if (j < end) {
        int s0 = csr_src[j];
        float hv0 = h2[(size_t)s0 * 32 + c];
        float l0 = ls[s0] + ldv;
        l0 = l0 > 0.f ? l0 : SLOPE * l0;
        float w0 = __expf(l0);
        sw0 += w0; swh0 += w0 * hv0;
    }
    float sw = sw0 + sw1, swh = swh0 + swh1;
    float r = sw > 0.f ? swh / sw : 0.f;
    out[(size_t)node * 32 + c] = r + b2[c];
}

// ---------------------------------------------------------------------------
extern "C" void kernel_launch(void* const* d_in, const int* in_sizes, int n_in,
                              void* d_out, int out_size, void* d_ws, size_t ws_size,
                              hipStream_t stream)
{
    const float* x      = (const float*)d_in[0];
    const int*   ei     = (const int*)  d_in[1];
    const float* W1     = (const float*)d_in[2];
    const float* a_src1 = (const float*)d_in[3];
    const float* a_dst1 = (const float*)d_in[4];
    const float* b1     = (const float*)d_in[5];
    const float* W2     = (const float*)d_in[6];
    const float* a_src2 = (const float*)d_in[7];
    const float* a_dst2 = (const float*)d_in[8];
    const float* b2     = (const float*)d_in[9];
    const int* src = ei;
    const int* dst = ei + N_EDGES;
    float* out = (float*)d_out;

    // workspace layout (4B words), total 7,350,528 = 29.4 MB.
    // Staging aliases h1/acc1: CSR build fully precedes k_gemm1 on the stream.
    float* ws   = (float*)d_ws;
    float* h1   = ws;                        // 3,200,000 f (stg_src aliases)
    float* acc1 = ws + 3200000;              // 3,200,000 f (stg_dst aliases)
    float* ls1  = ws + 6400000;              // 50,000 f
    float* ld1  = ws + 6450000;              // 50,000 f
    int* row_start   = (int*)(ws + 6500000); // 50,001 i (pad to 50,016)
    int* csr_src     = (int*)(ws + 6550016); // 800,000 i
    int* binctr      = (int*)(ws + 7350016); // 196 i (pad 256)
    int* bucket_base = (int*)(ws + 7350272); // 196 i (pad 256)
    int* stg_src = (int*)h1;                 // 196*4608 = 903,168 i
    int* stg_dst = (int*)acc1;
    float* h2  = h1;
    float* ls2 = ls1;
    float* ld2 = ld1;

    // CSR build (dst-sorted, reused by both layers)
    k_zerobins<<<1,   256,  0, stream>>>(binctr);
    k_bin     <<<98,  1024, 0, stream>>>(src, dst, binctr, stg_src, stg_dst);
    k_btot    <<<1,   256,  0, stream>>>(binctr, bucket_base);
    k_sort    <<<NBUCK, 1024, 0, stream>>>(stg_src, stg_dst, binctr, bucket_base,
                                           row_start, csr_src);

    // layer 1
    k_gemm1<<<782,   256, 0, stream>>>(x, W1, a_src1, a_dst1, h1, ls1, ld1);
    k_agg1 <<<12500, 256, 0, stream>>>(csr_src, row_start, ls1, ld1, h1, b1, acc1);

    // layer 2
    k_epi1 <<<782,  256, 0, stream>>>(acc1, W2, a_src2, a_dst2, h2, ls2, ld2);
    k_agg2 <<<6250, 256, 0, stream>>>(csr_src, row_start, ls2, ld2, h2, b2, out);
}

// Round 5
// 201.658 us; speedup vs baseline: 2.3672x; 1.1266x over previous
//
#include <hip/hip_runtime.h>

// 2-layer single-head GATConv, fp32, MI355X.
// N=50000 nodes, E=800000 edges, IN=128, HID=64, OUT=32.
//
// Round 4 -> 5: k_agg1 (53.5us, VALUBusy 43%) had 64 lanes redundantly
// computing each edge's exp(leakyrelu(...)) and a serial csr_src->gather
// chain. Restructured both agg kernels to lane-cooperative form: each lane
// loads ONE edge (coalesced csr_src) and computes its weight once; the
// denominator is a butterfly reduction; the numerator loop broadcasts
// (src, w) via wave-uniform __shfl (compiles to v_readlane -> SGPR-based
// gather) with 4 independent row-gathers in flight.

#define N_NODES 50000
#define N_EDGES 800000
#define SLOPE 0.2f
#define NBUCK 196           // ceil(50000/256) buckets of 256 dst nodes
#define CAP 4608            // staging capacity per bucket (mean 4096, sigma 64)

// ---------------------------------------------------------------------------
__global__ __launch_bounds__(256) void k_zerobins(int* __restrict__ binctr)
{
    if (threadIdx.x < NBUCK) binctr[threadIdx.x] = 0;
}

// Stage edges into per-bucket regions. 98 blocks x 1024 thr x 8 edges.
__global__ __launch_bounds__(1024) void k_bin(
    const int* __restrict__ src, const int* __restrict__ dst,
    int* __restrict__ binctr,
    int* __restrict__ stg_src, int* __restrict__ stg_dst)
{
    __shared__ int hist[NBUCK];
    __shared__ int gb[NBUCK];
    const int t = threadIdx.x;
    if (t < NBUCK) hist[t] = 0;
    __syncthreads();

    const int base = blockIdx.x * 8192;
    int ms[8], md[8], mr[8];
    int n = 0;
    #pragma unroll
    for (int k = 0; k < 8; ++k) {
        int e = base + t + k * 1024;
        if (e < N_EDGES) {
            int s = src[e], d = dst[e];
            ms[n] = s; md[n] = d;
            mr[n] = atomicAdd(&hist[d >> 8], 1);   // rank within block-bucket
            ++n;
        }
    }
    __syncthreads();
    if (t < NBUCK) gb[t] = atomicAdd(&binctr[t], hist[t]);  // reserve range
    __syncthreads();
    for (int i = 0; i < n; ++i) {
        int b = md[i] >> 8;
        int p = b * CAP + gb[b] + mr[i];
        stg_src[p] = ms[i];
        stg_dst[p] = md[i];
    }
}

// Exclusive scan of 196 bucket counts -> bucket_base.
__global__ __launch_bounds__(256) void k_btot(
    const int* __restrict__ binctr, int* __restrict__ bucket_base)
{
    __shared__ int tmp[256];
    const int t = threadIdx.x;
    int v = (t < NBUCK) ? binctr[t] : 0;
    tmp[t] = v;
    __syncthreads();
    #pragma unroll
    for (int off = 1; off < 256; off <<= 1) {
        int u = (t >= off) ? tmp[t - off] : 0;
        __syncthreads();
        tmp[t] += u;
        __syncthreads();
    }
    if (t < NBUCK) bucket_base[t] = tmp[t] - v;
}

// One block per bucket: counting-sort its 256 dst nodes in LDS, write
// contiguous csr_src slice + row_start for its nodes.
__global__ __launch_bounds__(1024) void k_sort(
    const int* __restrict__ stg_src, const int* __restrict__ stg_dst,
    const int* __restrict__ binctr, const int* __restrict__ bucket_base,
    int* __restrict__ row_start, int* __restrict__ csr_src)
{
    __shared__ int cnt[256];
    __shared__ int off[256];
    const int b = blockIdx.x, t = threadIdx.x;
    const int n = binctr[b];
    const int sbase = b * CAP;
    const int obase = bucket_base[b];

    if (t < 256) cnt[t] = 0;
    __syncthreads();

    int ms[5], mk[5], mr[5];
    int c = 0;
    for (int i = t; i < n; i += 1024) {
        int s = stg_src[sbase + i], d = stg_dst[sbase + i];
        int k = d & 255;
        ms[c] = s; mk[c] = k;
        mr[c] = atomicAdd(&cnt[k], 1);
        ++c;
    }
    __syncthreads();

    if (t < 256) off[t] = cnt[t];
    __syncthreads();
    #pragma unroll
    for (int o = 1; o < 256; o <<= 1) {
        int u = (t < 256 && t >= o) ? off[t - o] : 0;
        __syncthreads();
        if (t < 256) off[t] += u;
        __syncthreads();
    }
    // off = inclusive scan; exclusive prefix = off[k] - cnt[k]

    if (t < 256) {
        int node = b * 256 + t;
        if (node < N_NODES) row_start[node] = obase + off[t] - cnt[t];
    }
    if (b == NBUCK - 1 && t == 0) row_start[N_NODES] = N_EDGES;

    for (int i = 0; i < c; ++i)
        csr_src[obase + off[mk[i]] - cnt[mk[i]] + mr[i]] = ms[i];
}

// ---------------------------------------------------------------------------
// GEMM1: h1 = x @ W1  (50000x128 @ 128x64), fused ls1 = h1.a_src, ld1 = h1.a_dst
__global__ __launch_bounds__(256) void k_gemm1(
    const float* __restrict__ x, const float* __restrict__ W1,
    const float* __restrict__ a_src, const float* __restrict__ a_dst,
    float* __restrict__ h1, float* __restrict__ ls, float* __restrict__ ld)
{
    __shared__ float As[64][128];   // 32 KB
    __shared__ float Bs[128][64];   // 32 KB
    const int tid = threadIdx.x;
    const int m0 = blockIdx.x * 64;

    {   // W1 (128x64 = 2048 float4) -> Bs
        const float4* Wv = (const float4*)W1;
        float4* Bv = (float4*)&Bs[0][0];
        #pragma unroll
        for (int i = 0; i < 8; ++i) Bv[tid + i * 256] = Wv[tid + i * 256];
    }
    {   // x tile (64x128) -> As, coalesced float4, zero-pad past N
        const float4* Xv = (const float4*)x;
        #pragma unroll
        for (int i = 0; i < 8; ++i) {
            int idx = tid + i * 256;
            int r = idx >> 5, kq = idx & 31;        // 32 float4 per row
            float4 v = make_float4(0.f, 0.f, 0.f, 0.f);
            if (m0 + r < N_NODES) v = Xv[(size_t)(m0 + r) * 32 + kq];
            ((float4*)&As[r][0])[kq] = v;
        }
    }
    __syncthreads();

    const int tx = tid & 15, ty = tid >> 4;
    const int c0 = tx * 4, r0 = ty * 4;
    float acc[4][4] = {};
    for (int k = 0; k < 128; k += 4) {
        float a_s[4][4];
        #pragma unroll
        for (int i = 0; i < 4; ++i) {
            float4 av = *(const float4*)&As[r0 + i][k];
            a_s[i][0] = av.x; a_s[i][1] = av.y; a_s[i][2] = av.z; a_s[i][3] = av.w;
        }
        #pragma unroll
        for (int kk = 0; kk < 4; ++kk) {
            float4 b = *(const float4*)&Bs[k + kk][c0];
            #pragma unroll
            for (int i = 0; i < 4; ++i) {
                acc[i][0] += a_s[i][kk] * b.x;
                acc[i][1] += a_s[i][kk] * b.y;
                acc[i][2] += a_s[i][kk] * b.z;
                acc[i][3] += a_s[i][kk] * b.w;
            }
        }
    }

    float as4[4], ad4[4];
    #pragma unroll
    for (int j = 0; j < 4; ++j) { as4[j] = a_src[c0 + j]; ad4[j] = a_dst[c0 + j]; }

    #pragma unroll
    for (int i = 0; i < 4; ++i) {
        int row = m0 + r0 + i;
        float pls = acc[i][0]*as4[0] + acc[i][1]*as4[1] + acc[i][2]*as4[2] + acc[i][3]*as4[3];
        float pld = acc[i][0]*ad4[0] + acc[i][1]*ad4[1] + acc[i][2]*ad4[2] + acc[i][3]*ad4[3];
        #pragma unroll
        for (int off = 1; off < 16; off <<= 1) {
            pls += __shfl_xor(pls, off, 64);
            pld += __shfl_xor(pld, off, 64);
        }
        if (row < N_NODES) {
            ((float4*)&h1[(size_t)row * 64])[tx] =
                make_float4(acc[i][0], acc[i][1], acc[i][2], acc[i][3]);
            if (tx == 0) { ls[row] = pls; ld[row] = pld; }
        }
    }
}

// ---------------------------------------------------------------------------
// Aggregate layer 1 (C=64): one wave per dst node, lane-cooperative edges.
__global__ __launch_bounds__(256) void k_agg1(
    const int* __restrict__ csr_src, const int* __restrict__ row_start,
    const float* __restrict__ ls, const float* __restrict__ ld,
    const float* __restrict__ h1, const float* __restrict__ b1,
    float* __restrict__ acc1)
{
    const int node = blockIdx.x * 4 + (threadIdx.x >> 6);  // 12500*4 == N_NODES
    const int lane = threadIdx.x & 63;
    const int beg = row_start[node], end = row_start[node + 1];
    const float ldv = ld[node];

    float acc = 0.f, sw = 0.f;
    for (int base = beg; base < end; base += 64) {
        const int cnt = min(64, end - base);
        int s = 0;
        float w = 0.f;
        if (lane < cnt) {
            s = csr_src[base + lane];              // coalesced
            float l = ls[s] + ldv;                 // one exp per EDGE, not 64
            l = l > 0.f ? l : SLOPE * l;
            w = __expf(l);
        }
        float wsum = w;                            // denominator via butterfly
        #pragma unroll
        for (int off = 1; off < 64; off <<= 1) wsum += __shfl_xor(wsum, off, 64);
        sw += wsum;

        int j = 0;                                 // numerator: broadcast + gather
        for (; j + 4 <= cnt; j += 4) {
            int s0 = __shfl(s, j, 64),     s1 = __shfl(s, j + 1, 64);
            int s2 = __shfl(s, j + 2, 64), s3 = __shfl(s, j + 3, 64);
            float w0 = __shfl(w, j, 64),     w1 = __shfl(w, j + 1, 64);
            float w2 = __shfl(w, j + 2, 64), w3 = __shfl(w, j + 3, 64);
            float g0 = h1[(size_t)s0 * 64 + lane];
            float g1 = h1[(size_t)s1 * 64 + lane];
            float g2 = h1[(size_t)s2 * 64 + lane];
            float g3 = h1[(size_t)s3 * 64 + lane];
            acc += w0 * g0; acc += w1 * g1; acc += w2 * g2; acc += w3 * g3;
        }
        for (; j < cnt; ++j) {
            int sj = __shfl(s, j, 64);
            float wj = __shfl(w, j, 64);
            acc += wj * h1[(size_t)sj * 64 + lane];
        }
    }
    float r = sw > 0.f ? acc / sw : 0.f;
    acc1[(size_t)node * 64 + lane] = r + b1[lane];
}

// ---------------------------------------------------------------------------
// Epilogue layer1 + GEMM2: h2 = relu(acc1) @ W2, fused ls2/ld2.
__global__ __launch_bounds__(256) void k_epi1(
    const float* __restrict__ acc1, const float* __restrict__ W2,
    const float* __restrict__ a_src2, const float* __restrict__ a_dst2,
    float* __restrict__ h2, float* __restrict__ ls2, float* __restrict__ ld2)
{
    __shared__ float Hs[64][68];
    __shared__ float W2s[64][32];
    const int tid = threadIdx.x;
    const int n0 = blockIdx.x * 64;

    {   // W2 (64x32 = 512 float4) -> LDS
        const float4* Wv = (const float4*)W2;
        float4* Ws = (float4*)&W2s[0][0];
        Ws[tid] = Wv[tid];
        Ws[tid + 256] = Wv[tid + 256];
    }
    {   // relu(acc1 rows) -> Hs, coalesced
        const float4* Av = (const float4*)acc1;
        #pragma unroll
        for (int i = 0; i < 4; ++i) {
            int idx = tid + i * 256;
            int r = idx >> 4, kq = idx & 15;
            float4 v = make_float4(0.f, 0.f, 0.f, 0.f);
            if (n0 + r < N_NODES) {
                v = Av[(size_t)(n0 + r) * 16 + kq];
                v.x = fmaxf(v.x, 0.f); v.y = fmaxf(v.y, 0.f);
                v.z = fmaxf(v.z, 0.f); v.w = fmaxf(v.w, 0.f);
            }
            ((float4*)&Hs[r][0])[kq] = v;
        }
    }
    __syncthreads();

    const int nl = tid >> 2, cg = tid & 3, c0 = cg * 8;
    float acc[8] = {};
    for (int k4 = 0; k4 < 16; ++k4) {
        float4 hv4 = *(const float4*)&Hs[nl][k4 * 4];
        #pragma unroll
        for (int kk = 0; kk < 4; ++kk) {
            float hv = kk == 0 ? hv4.x : kk == 1 ? hv4.y : kk == 2 ? hv4.z : hv4.w;
            int k = k4 * 4 + kk;
            float4 w0 = *(const float4*)&W2s[k][c0];
            float4 w1 = *(const float4*)&W2s[k][c0 + 4];
            acc[0] += hv * w0.x; acc[1] += hv * w0.y;
            acc[2] += hv * w0.z; acc[3] += hv * w0.w;
            acc[4] += hv * w1.x; acc[5] += hv * w1.y;
            acc[6] += hv * w1.z; acc[7] += hv * w1.w;
        }
    }

    float pls = 0.f, pld = 0.f;
    #pragma unroll
    for (int j = 0; j < 8; ++j) {
        pls += acc[j] * a_src2[c0 + j];
        pld += acc[j] * a_dst2[c0 + j];
    }
    pls += __shfl_xor(pls, 1, 64); pls += __shfl_xor(pls, 2, 64);
    pld += __shfl_xor(pld, 1, 64); pld += __shfl_xor(pld, 2, 64);

    int node = n0 + nl;
    if (node < N_NODES) {
        ((float4*)&h2[(size_t)node * 32])[cg * 2] =
            make_float4(acc[0], acc[1], acc[2], acc[3]);
        ((float4*)&h2[(size_t)node * 32])[cg * 2 + 1] =
            make_float4(acc[4], acc[5], acc[6], acc[7]);
        if (cg == 0) { ls2[node] = pls; ld2[node] = pld; }
    }
}

// ---------------------------------------------------------------------------
// Aggregate layer 2 (C=32): one 32-lane group per dst node, lane-cooperative.
__global__ __launch_bounds__(256) void k_agg2(
    const int* __restrict__ csr_src, const int* __restrict__ row_start,
    const float* __restrict__ ls, const float* __restrict__ ld,
    const float* __restrict__ h2, const float* __restrict__ b2,
    float* __restrict__ out)
{
    const int idx = blockIdx.x * 256 + threadIdx.x;   // 6250*256 == N*32
    const int node = idx >> 5;
    const int c = idx & 31;
    const int beg = row_start[node], end = row_start[node + 1];
    const float ldv = ld[node];

    float acc = 0.f, sw = 0.f;
    for (int base = beg; base < end; base += 32) {
        const int cnt = min(32, end - base);
        int s = 0;
        float w = 0.f;
        if (c < cnt) {
            s = csr_src[base + c];
            float l = ls[s] + ldv;
            l = l > 0.f ? l : SLOPE * l;
            w = __expf(l);
        }
        float wsum = w;
        #pragma unroll
        for (int off = 1; off < 32; off <<= 1) wsum += __shfl_xor(wsum, off, 32);
        sw += wsum;

        int j = 0;
        for (; j + 4 <= cnt; j += 4) {
            int s0 = __shfl(s, j, 32),     s1 = __shfl(s, j + 1, 32);
            int s2 = __shfl(s, j + 2, 32), s3 = __shfl(s, j + 3, 32);
            float w0 = __shfl(w, j, 32),     w1 = __shfl(w, j + 1, 32);
            float w2 = __shfl(w, j + 2, 32), w3 = __shfl(w, j + 3, 32);
            float g0 = h2[(size_t)s0 * 32 + c];
            float g1 = h2[(size_t)s1 * 32 + c];
            float g2 = h2[(size_t)s2 * 32 + c];
            float g3 = h2[(size_t)s3 * 32 + c];
            acc += w0 * g0; acc += w1 * g1; acc += w2 * g2; acc += w3 * g3;
        }
        for (; j < cnt; ++j) {
            int sj = __shfl(s, j, 32);
            float wj = __shfl(w, j, 32);
            acc += wj * h2[(size_t)sj * 32 + c];
        }
    }
    float r = sw > 0.f ? acc / sw : 0.f;
    out[(size_t)node * 32 + c] = r + b2[c];
}

// ---------------------------------------------------------------------------
extern "C" void kernel_launch(void* const* d_in, const int* in_sizes, int n_in,
                              void* d_out, int out_size, void* d_ws, size_t ws_size,
                              hipStream_t stream)
{
    const float* x      = (const float*)d_in[0];
    const int*   ei     = (const int*)  d_in[1];
    const float* W1     = (const float*)d_in[2];
    const float* a_src1 = (const float*)d_in[3];
    const float* a_dst1 = (const float*)d_in[4];
    const float* b1     = (const float*)d_in[5];
    const float* W2     = (const float*)d_in[6];
    const float* a_src2 = (const float*)d_in[7];
    const float* a_dst2 = (const float*)d_in[8];
    const float* b2     = (const float*)d_in[9];
    const int* src = ei;
    const int* dst = ei + N_EDGES;
    float* out = (float*)d_out;

    // workspace layout (4B words), total 7,350,528 = 29.4 MB.
    // Staging aliases h1/acc1: CSR build fully precedes k_gemm1 on the stream.
    float* ws   = (float*)d_ws;
    float* h1   = ws;                        // 3,200,000 f (stg_src aliases)
    float* acc1 = ws + 3200000;              // 3,200,000 f (stg_dst aliases)
    float* ls1  = ws + 6400000;              // 50,000 f
    float* ld1  = ws + 6450000;              // 50,000 f
    int* row_start   = (int*)(ws + 6500000); // 50,001 i (pad to 50,016)
    int* csr_src     = (int*)(ws + 6550016); // 800,000 i
    int* binctr      = (int*)(ws + 7350016); // 196 i (pad 256)
    int* bucket_base = (int*)(ws + 7350272); // 196 i (pad 256)
    int* stg_src = (int*)h1;                 // 196*4608 = 903,168 i
    int* stg_dst = (int*)acc1;
    float* h2  = h1;
    float* ls2 = ls1;
    float* ld2 = ld1;

    // CSR build (dst-sorted, reused by both layers)
    k_zerobins<<<1,   256,  0, stream>>>(binctr);
    k_bin     <<<98,  1024, 0, stream>>>(src, dst, binctr, stg_src, stg_dst);
    k_btot    <<<1,   256,  0, stream>>>(binctr, bucket_base);
    k_sort    <<<NBUCK, 1024, 0, stream>>>(stg_src, stg_dst, binctr, bucket_base,
                                           row_start, csr_src);

    // layer 1
    k_gemm1<<<782,   256, 0, stream>>>(x, W1, a_src1, a_dst1, h1, ls1, ld1);
    k_agg1 <<<12500, 256, 0, stream>>>(csr_src, row_start, ls1, ld1, h1, b1, acc1);

    // layer 2
    k_epi1 <<<782,  256, 0, stream>>>(acc1, W2, a_src2, a_dst2, h2, ls2, ld2);
    k_agg2 <<<6250, 256, 0, stream>>>(csr_src, row_start, ls2, ld2, h2, b2, out);
}

// Round 6
// 190.723 us; speedup vs baseline: 2.5029x; 1.0573x over previous
//
#include <hip/hip_runtime.h>

// 2-layer single-head GATConv, fp32, MI355X.
// N=50000 nodes, E=800000 edges, IN=128, HID=64, OUT=32.
//
// Round 5 -> 6:
//  (a) agg kernels: float4 row-gathers with 4 edge-slots per node group.
//      Lane = (eslot, c4): 16 (resp. 8) lanes fetch a row as dwordx4 while
//      4 slots process 4 different edges concurrently -> ~3x fewer
//      instructions per edge, 4 independent row gathers in flight; final
//      cross-slot shfl_xor reduction.
//  (b) bucket staging packed to ONE int: s | ((d&255)<<16)  (s < 2^16,
//      bucket = blockIdx at sort time) -> halves staging traffic.

#define N_NODES 50000
#define N_EDGES 800000
#define SLOPE 0.2f
#define NBUCK 196           // ceil(50000/256) buckets of 256 dst nodes
#define CAP 4608            // staging capacity per bucket (mean 4096, sigma 64)

// ---------------------------------------------------------------------------
__global__ __launch_bounds__(256) void k_zerobins(int* __restrict__ binctr)
{
    if (threadIdx.x < NBUCK) binctr[threadIdx.x] = 0;
}

// Stage edges into per-bucket regions. 98 blocks x 1024 thr x 8 edges.
__global__ __launch_bounds__(1024) void k_bin(
    const int* __restrict__ src, const int* __restrict__ dst,
    int* __restrict__ binctr, int* __restrict__ stg)
{
    __shared__ int hist[NBUCK];
    __shared__ int gb[NBUCK];
    const int t = threadIdx.x;
    if (t < NBUCK) hist[t] = 0;
    __syncthreads();

    const int base = blockIdx.x * 8192;
    int mp[8], mb[8], mr[8];
    int n = 0;
    #pragma unroll
    for (int k = 0; k < 8; ++k) {
        int e = base + t + k * 1024;
        if (e < N_EDGES) {
            int s = src[e], d = dst[e];
            int b = d >> 8;
            mp[n] = s | ((d & 255) << 16);         // s fits in 16 bits
            mb[n] = b;
            mr[n] = atomicAdd(&hist[b], 1);        // rank within block-bucket
            ++n;
        }
    }
    __syncthreads();
    if (t < NBUCK) gb[t] = atomicAdd(&binctr[t], hist[t]);  // reserve range
    __syncthreads();
    for (int i = 0; i < n; ++i)
        stg[mb[i] * CAP + gb[mb[i]] + mr[i]] = mp[i];
}

// Exclusive scan of 196 bucket counts -> bucket_base.
__global__ __launch_bounds__(256) void k_btot(
    const int* __restrict__ binctr, int* __restrict__ bucket_base)
{
    __shared__ int tmp[256];
    const int t = threadIdx.x;
    int v = (t < NBUCK) ? binctr[t] : 0;
    tmp[t] = v;
    __syncthreads();
    #pragma unroll
    for (int off = 1; off < 256; off <<= 1) {
        int u = (t >= off) ? tmp[t - off] : 0;
        __syncthreads();
        tmp[t] += u;
        __syncthreads();
    }
    if (t < NBUCK) bucket_base[t] = tmp[t] - v;
}

// One block per bucket: counting-sort its 256 dst nodes in LDS, write
// contiguous csr_src slice + row_start for its nodes.
__global__ __launch_bounds__(1024) void k_sort(
    const int* __restrict__ stg,
    const int* __restrict__ binctr, const int* __restrict__ bucket_base,
    int* __restrict__ row_start, int* __restrict__ csr_src)
{
    __shared__ int cnt[256];
    __shared__ int off[256];
    const int b = blockIdx.x, t = threadIdx.x;
    const int n = binctr[b];
    const int sbase = b * CAP;
    const int obase = bucket_base[b];

    if (t < 256) cnt[t] = 0;
    __syncthreads();

    int mv[5], mk[5], mr[5];
    int c = 0;
    for (int i = t; i < n; i += 1024) {
        int v = stg[sbase + i];
        int k = v >> 16;                 // dst & 255
        mv[c] = v & 0xFFFF;              // src
        mk[c] = k;
        mr[c] = atomicAdd(&cnt[k], 1);
        ++c;
    }
    __syncthreads();

    if (t < 256) off[t] = cnt[t];
    __syncthreads();
    #pragma unroll
    for (int o = 1; o < 256; o <<= 1) {
        int u = (t < 256 && t >= o) ? off[t - o] : 0;
        __syncthreads();
        if (t < 256) off[t] += u;
        __syncthreads();
    }
    // off = inclusive scan; exclusive prefix = off[k] - cnt[k]

    if (t < 256) {
        int node = b * 256 + t;
        if (node < N_NODES) row_start[node] = obase + off[t] - cnt[t];
    }
    if (b == NBUCK - 1 && t == 0) row_start[N_NODES] = N_EDGES;

    for (int i = 0; i < c; ++i)
        csr_src[obase + off[mk[i]] - cnt[mk[i]] + mr[i]] = mv[i];
}

// ---------------------------------------------------------------------------
// GEMM1: h1 = x @ W1  (50000x128 @ 128x64), fused ls1 = h1.a_src, ld1 = h1.a_dst
__global__ __launch_bounds__(256) void k_gemm1(
    const float* __restrict__ x, const float* __restrict__ W1,
    const float* __restrict__ a_src, const float* __restrict__ a_dst,
    float* __restrict__ h1, float* __restrict__ ls, float* __restrict__ ld)
{
    __shared__ float As[64][128];   // 32 KB
    __shared__ float Bs[128][64];   // 32 KB
    const int tid = threadIdx.x;
    const int m0 = blockIdx.x * 64;

    {   // W1 (128x64 = 2048 float4) -> Bs
        const float4* Wv = (const float4*)W1;
        float4* Bv = (float4*)&Bs[0][0];
        #pragma unroll
        for (int i = 0; i < 8; ++i) Bv[tid + i * 256] = Wv[tid + i * 256];
    }
    {   // x tile (64x128) -> As, coalesced float4, zero-pad past N
        const float4* Xv = (const float4*)x;
        #pragma unroll
        for (int i = 0; i < 8; ++i) {
            int idx = tid + i * 256;
            int r = idx >> 5, kq = idx & 31;        // 32 float4 per row
            float4 v = make_float4(0.f, 0.f, 0.f, 0.f);
            if (m0 + r < N_NODES) v = Xv[(size_t)(m0 + r) * 32 + kq];
            ((float4*)&As[r][0])[kq] = v;
        }
    }
    __syncthreads();

    const int tx = tid & 15, ty = tid >> 4;
    const int c0 = tx * 4, r0 = ty * 4;
    float acc[4][4] = {};
    for (int k = 0; k < 128; k += 4) {
        float a_s[4][4];
        #pragma unroll
        for (int i = 0; i < 4; ++i) {
            float4 av = *(const float4*)&As[r0 + i][k];
            a_s[i][0] = av.x; a_s[i][1] = av.y; a_s[i][2] = av.z; a_s[i][3] = av.w;
        }
        #pragma unroll
        for (int kk = 0; kk < 4; ++kk) {
            float4 b = *(const float4*)&Bs[k + kk][c0];
            #pragma unroll
            for (int i = 0; i < 4; ++i) {
                acc[i][0] += a_s[i][kk] * b.x;
                acc[i][1] += a_s[i][kk] * b.y;
                acc[i][2] += a_s[i][kk] * b.z;
                acc[i][3] += a_s[i][kk] * b.w;
            }
        }
    }

    float as4[4], ad4[4];
    #pragma unroll
    for (int j = 0; j < 4; ++j) { as4[j] = a_src[c0 + j]; ad4[j] = a_dst[c0 + j]; }

    #pragma unroll
    for (int i = 0; i < 4; ++i) {
        int row = m0 + r0 + i;
        float pls = acc[i][0]*as4[0] + acc[i][1]*as4[1] + acc[i][2]*as4[2] + acc[i][3]*as4[3];
        float pld = acc[i][0]*ad4[0] + acc[i][1]*ad4[1] + acc[i][2]*ad4[2] + acc[i][3]*ad4[3];
        #pragma unroll
        for (int off = 1; off < 16; off <<= 1) {
            pls += __shfl_xor(pls, off, 64);
            pld += __shfl_xor(pld, off, 64);
        }
        if (row < N_NODES) {
            ((float4*)&h1[(size_t)row * 64])[tx] =
                make_float4(acc[i][0], acc[i][1], acc[i][2], acc[i][3]);
            if (tx == 0) { ls[row] = pls; ld[row] = pld; }
        }
    }
}

// ---------------------------------------------------------------------------
// Aggregate layer 1 (C=64): one wave per dst node.
// Lane = (eslot = lane>>4, c4 = lane&15): 16 lanes gather a row as float4,
// 4 slots process 4 different edges concurrently.
__global__ __launch_bounds__(256) void k_agg1(
    const int* __restrict__ csr_src, const int* __restrict__ row_start,
    const float* __restrict__ ls, const float* __restrict__ ld,
    const float* __restrict__ h1, const float* __restrict__ b1,
    float* __restrict__ acc1)
{
    const int node = blockIdx.x * 4 + (threadIdx.x >> 6);  // 12500*4 == N_NODES
    const int lane = threadIdx.x & 63;
    const int c4 = lane & 15, eslot = lane >> 4;
    const int beg = row_start[node], end = row_start[node + 1];
    const float ldv = ld[node];
    const float4* H = (const float4*)h1;

    float4 acc = make_float4(0.f, 0.f, 0.f, 0.f);
    float sw = 0.f;
    for (int base = beg; base < end; base += 64) {
        const int cnt = min(64, end - base);
        int s = 0;
        float w = 0.f;
        if (lane < cnt) {
            s = csr_src[base + lane];              // coalesced
            float l = ls[s] + ldv;                 // one exp per EDGE
            l = l > 0.f ? l : SLOPE * l;
            w = __expf(l);
        }
        float wsum = w;                            // denominator via butterfly
        #pragma unroll
        for (int off = 1; off < 64; off <<= 1) wsum += __shfl_xor(wsum, off, 64);
        sw += wsum;

        int j = 0;                                 // 8 edges per iter (2/slot)
        for (; j + 8 <= cnt; j += 8) {
            int   s0 = __shfl(s, j + eslot, 64);
            int   s1 = __shfl(s, j + 4 + eslot, 64);
            float w0 = __shfl(w, j + eslot, 64);
            float w1 = __shfl(w, j + 4 + eslot, 64);
            float4 g0 = H[(size_t)s0 * 16 + c4];
            float4 g1 = H[(size_t)s1 * 16 + c4];
            acc.x += w0 * g0.x; acc.y += w0 * g0.y;
            acc.z += w0 * g0.z; acc.w += w0 * g0.w;
            acc.x += w1 * g1.x; acc.y += w1 * g1.y;
            acc.z += w1 * g1.z; acc.w += w1 * g1.w;
        }
        for (; j < cnt; j += 4) {                  // tail: invalid slots have w=0
            int   sj = __shfl(s, j + eslot, 64);
            float wj = __shfl(w, j + eslot, 64);
            float4 g = H[(size_t)sj * 16 + c4];
            acc.x += wj * g.x; acc.y += wj * g.y;
            acc.z += wj * g.z; acc.w += wj * g.w;
        }
    }
    // reduce across the 4 edge slots (xor bits 4,5)
    #pragma unroll
    for (int off = 16; off < 64; off <<= 1) {
        acc.x += __shfl_xor(acc.x, off, 64);
        acc.y += __shfl_xor(acc.y, off, 64);
        acc.z += __shfl_xor(acc.z, off, 64);
        acc.w += __shfl_xor(acc.w, off, 64);
    }
    if (eslot == 0) {
        float inv = sw > 0.f ? 1.f / sw : 0.f;
        float4 bb = ((const float4*)b1)[c4];
        ((float4*)&acc1[(size_t)node * 64])[c4] =
            make_float4(acc.x * inv + bb.x, acc.y * inv + bb.y,
                        acc.z * inv + bb.z, acc.w * inv + bb.w);
    }
}

// ---------------------------------------------------------------------------
// Epilogue layer1 + GEMM2: h2 = relu(acc1) @ W2, fused ls2/ld2.
__global__ __launch_bounds__(256) void k_epi1(
    const float* __restrict__ acc1, const float* __restrict__ W2,
    const float* __restrict__ a_src2, const float* __restrict__ a_dst2,
    float* __restrict__ h2, float* __restrict__ ls2, float* __restrict__ ld2)
{
    __shared__ float Hs[64][68];
    __shared__ float W2s[64][32];
    const int tid = threadIdx.x;
    const int n0 = blockIdx.x * 64;

    {   // W2 (64x32 = 512 float4) -> LDS
        const float4* Wv = (const float4*)W2;
        float4* Ws = (float4*)&W2s[0][0];
        Ws[tid] = Wv[tid];
        Ws[tid + 256] = Wv[tid + 256];
    }
    {   // relu(acc1 rows) -> Hs, coalesced
        const float4* Av = (const float4*)acc1;
        #pragma unroll
        for (int i = 0; i < 4; ++i) {
            int idx = tid + i * 256;
            int r = idx >> 4, kq = idx & 15;
            float4 v = make_float4(0.f, 0.f, 0.f, 0.f);
            if (n0 + r < N_NODES) {
                v = Av[(size_t)(n0 + r) * 16 + kq];
                v.x = fmaxf(v.x, 0.f); v.y = fmaxf(v.y, 0.f);
                v.z = fmaxf(v.z, 0.f); v.w = fmaxf(v.w, 0.f);
            }
            ((float4*)&Hs[r][0])[kq] = v;
        }
    }
    __syncthreads();

    const int nl = tid >> 2, cg = tid & 3, c0 = cg * 8;
    float acc[8] = {};
    for (int k4 = 0; k4 < 16; ++k4) {
        float4 hv4 = *(const float4*)&Hs[nl][k4 * 4];
        #pragma unroll
        for (int kk = 0; kk < 4; ++kk) {
            float hv = kk == 0 ? hv4.x : kk == 1 ? hv4.y : kk == 2 ? hv4.z : hv4.w;
            int k = k4 * 4 + kk;
            float4 w0 = *(const float4*)&W2s[k][c0];
            float4 w1 = *(const float4*)&W2s[k][c0 + 4];
            acc[0] += hv * w0.x; acc[1] += hv * w0.y;
            acc[2] += hv * w0.z; acc[3] += hv * w0.w;
            acc[4] += hv * w1.x; acc[5] += hv * w1.y;
            acc[6] += hv * w1.z; acc[7] += hv * w1.w;
        }
    }

    float pls = 0.f, pld = 0.f;
    #pragma unroll
    for (int j = 0; j < 8; ++j) {
        pls += acc[j] * a_src2[c0 + j];
        pld += acc[j] * a_dst2[c0 + j];
    }
    pls += __shfl_xor(pls, 1, 64); pls += __shfl_xor(pls, 2, 64);
    pld += __shfl_xor(pld, 1, 64); pld += __shfl_xor(pld, 2, 64);

    int node = n0 + nl;
    if (node < N_NODES) {
        ((float4*)&h2[(size_t)node * 32])[cg * 2] =
            make_float4(acc[0], acc[1], acc[2], acc[3]);
        ((float4*)&h2[(size_t)node * 32])[cg * 2 + 1] =
            make_float4(acc[4], acc[5], acc[6], acc[7]);
        if (cg == 0) { ls2[node] = pls; ld2[node] = pld; }
    }
}

// ---------------------------------------------------------------------------
// Aggregate layer 2 (C=32): one 32-lane group per dst node.
// Within group: c4 = grp&7 (8 float4 channel groups), eslot = grp>>3 (4 slots).
__global__ __launch_bounds__(256) void k_agg2(
    const int* __restrict__ csr_src, const int* __restrict__ row_start,
    const float* __restrict__ ls, const float* __restrict__ ld,
    const float* __restrict__ h2, const float* __restrict__ b2,
    float* __restrict__ out)
{
    const int idx = blockIdx.x * 256 + threadIdx.x;   // 6250*256 == N*32
    const int node = idx >> 5;
    const int grp = idx & 31;
    const int c4 = grp & 7, eslot = grp >> 3;
    const int beg = row_start[node], end = row_start[node + 1];
    const float ldv = ld[node];
    const float4* H = (const float4*)h2;

    float4 acc = make_float4(0.f, 0.f, 0.f, 0.f);
    float sw = 0.f;
    for (int base = beg; base < end; base += 32) {
        const int cnt = min(32, end - base);
        int s = 0;
        float w = 0.f;
        if (grp < cnt) {
            s = csr_src[base + grp];
            float l = ls[s] + ldv;
            l = l > 0.f ? l : SLOPE * l;
            w = __expf(l);
        }
        float wsum = w;
        #pragma unroll
        for (int off = 1; off < 32; off <<= 1) wsum += __shfl_xor(wsum, off, 32);
        sw += wsum;

        int j = 0;
        for (; j + 8 <= cnt; j += 8) {
            int   s0 = __shfl(s, j + eslot, 32);
            int   s1 = __shfl(s, j + 4 + eslot, 32);
            float w0 = __shfl(w, j + eslot, 32);
            float w1 = __shfl(w, j + 4 + eslot, 32);
            float4 g0 = H[(size_t)s0 * 8 + c4];
            float4 g1 = H[(size_t)s1 * 8 + c4];
            acc.x += w0 * g0.x; acc.y += w0 * g0.y;
            acc.z += w0 * g0.z; acc.w += w0 * g0.w;
            acc.x += w1 * g1.x; acc.y += w1 * g1.y;
            acc.z += w1 * g1.z; acc.w += w1 * g1.w;
        }
        for (; j < cnt; j += 4) {
            int   sj = __shfl(s, j + eslot, 32);
            float wj = __shfl(w, j + eslot, 32);
            float4 g = H[(size_t)sj * 8 + c4];
            acc.x += wj * g.x; acc.y += wj * g.y;
            acc.z += wj * g.z; acc.w += wj * g.w;
        }
    }
    // reduce across the 4 edge slots (xor bits 3,4 of grp)
    #pragma unroll
    for (int off = 8; off < 32; off <<= 1) {
        acc.x += __shfl_xor(acc.x, off, 32);
        acc.y += __shfl_xor(acc.y, off, 32);
        acc.z += __shfl_xor(acc.z, off, 32);
        acc.w += __shfl_xor(acc.w, off, 32);
    }
    if (eslot == 0) {
        float inv = sw > 0.f ? 1.f / sw : 0.f;
        float4 bb = ((const float4*)b2)[c4];
        ((float4*)&out[(size_t)node * 32])[c4] =
            make_float4(acc.x * inv + bb.x, acc.y * inv + bb.y,
                        acc.z * inv + bb.z, acc.w * inv + bb.w);
    }
}

// ---------------------------------------------------------------------------
extern "C" void kernel_launch(void* const* d_in, const int* in_sizes, int n_in,
                              void* d_out, int out_size, void* d_ws, size_t ws_size,
                              hipStream_t stream)
{
    const float* x      = (const float*)d_in[0];
    const int*   ei     = (const int*)  d_in[1];
    const float* W1     = (const float*)d_in[2];
    const float* a_src1 = (const float*)d_in[3];
    const float* a_dst1 = (const float*)d_in[4];
    const float* b1     = (const float*)d_in[5];
    const float* W2     = (const float*)d_in[6];
    const float* a_src2 = (const float*)d_in[7];
    const float* a_dst2 = (const float*)d_in[8];
    const float* b2     = (const float*)d_in[9];
    const int* src = ei;
    const int* dst = ei + N_EDGES;
    float* out = (float*)d_out;

    // workspace layout (4B words), total 7,350,528 = 29.4 MB.
    // Staging aliases h1: CSR build fully precedes k_gemm1 on the stream.
    float* ws   = (float*)d_ws;
    float* h1   = ws;                        // 3,200,000 f (stg aliases)
    float* acc1 = ws + 3200000;              // 3,200,000 f
    float* ls1  = ws + 6400000;              // 50,000 f
    float* ld1  = ws + 6450000;              // 50,000 f
    int* row_start   = (int*)(ws + 6500000); // 50,001 i (pad to 50,016)
    int* csr_src     = (int*)(ws + 6550016); // 800,000 i
    int* binctr      = (int*)(ws + 7350016); // 196 i (pad 256)
    int* bucket_base = (int*)(ws + 7350272); // 196 i (pad 256)
    int* stg = (int*)h1;                     // 196*4608 = 903,168 i
    float* h2  = h1;
    float* ls2 = ls1;
    float* ld2 = ld1;

    // CSR build (dst-sorted, reused by both layers)
    k_zerobins<<<1,   256,  0, stream>>>(binctr);
    k_bin     <<<98,  1024, 0, stream>>>(src, dst, binctr, stg);
    k_btot    <<<1,   256,  0, stream>>>(binctr, bucket_base);
    k_sort    <<<NBUCK, 1024, 0, stream>>>(stg, binctr, bucket_base,
                                           row_start, csr_src);

    // layer 1
    k_gemm1<<<782,   256, 0, stream>>>(x, W1, a_src1, a_dst1, h1, ls1, ld1);
    k_agg1 <<<12500, 256, 0, stream>>>(csr_src, row_start, ls1, ld1, h1, b1, acc1);

    // layer 2
    k_epi1 <<<782,  256, 0, stream>>>(acc1, W2, a_src2, a_dst2, h2, ls2, ld2);
    k_agg2 <<<6250, 256, 0, stream>>>(csr_src, row_start, ls2, ld2, h2, b2, out);
}

// Round 7
// 181.534 us; speedup vs baseline: 2.6296x; 1.0506x over previous
//
#include <hip/hip_runtime.h>
#include <hip/hip_fp16.h>

// 2-layer single-head GATConv, fp32 in/out, MI355X.
// N=50000 nodes, E=800000 edges, IN=128, HID=64, OUT=32.
//
// Round 6 -> 7: h1 and h2 are ONLY consumed by the random row-gathers in the
// agg kernels (ls/ld are fused into gemm1/epi1; epi1 reads acc1). Store them
// as fp16 rows: gather bytes halve (agg1 205->102 MB logical, agg2 102->51),
// h write traffic halves. fp16 rel eps 4.9e-4 at |h|~O(3) adds ~1e-3 absmax
// against a 2.1e-2 threshold (measured 3.9e-3 before this change).
// Accumulation stays fp32 throughout.

#define N_NODES 50000
#define N_EDGES 800000
#define SLOPE 0.2f
#define NBUCK 196           // ceil(50000/256) buckets of 256 dst nodes
#define CAP 4608            // staging capacity per bucket (mean 4096, sigma 64)

typedef _Float16 half4 __attribute__((ext_vector_type(4)));

// ---------------------------------------------------------------------------
__global__ __launch_bounds__(256) void k_zerobins(int* __restrict__ binctr)
{
    if (threadIdx.x < NBUCK) binctr[threadIdx.x] = 0;
}

// Stage edges into per-bucket regions. 98 blocks x 1024 thr x 8 edges.
// Packed: s | ((d&255)<<16), bucket = d>>8 is implicit in the staging slot.
__global__ __launch_bounds__(1024) void k_bin(
    const int* __restrict__ src, const int* __restrict__ dst,
    int* __restrict__ binctr, int* __restrict__ stg)
{
    __shared__ int hist[NBUCK];
    __shared__ int gb[NBUCK];
    const int t = threadIdx.x;
    if (t < NBUCK) hist[t] = 0;
    __syncthreads();

    const int base = blockIdx.x * 8192;
    int mp[8], mb[8], mr[8];
    int n = 0;
    #pragma unroll
    for (int k = 0; k < 8; ++k) {
        int e = base + t + k * 1024;
        if (e < N_EDGES) {
            int s = src[e], d = dst[e];
            int b = d >> 8;
            mp[n] = s | ((d & 255) << 16);         // s fits in 16 bits
            mb[n] = b;
            mr[n] = atomicAdd(&hist[b], 1);        // rank within block-bucket
            ++n;
        }
    }
    __syncthreads();
    if (t < NBUCK) gb[t] = atomicAdd(&binctr[t], hist[t]);  // reserve range
    __syncthreads();
    for (int i = 0; i < n; ++i)
        stg[mb[i] * CAP + gb[mb[i]] + mr[i]] = mp[i];
}

// Exclusive scan of 196 bucket counts -> bucket_base.
__global__ __launch_bounds__(256) void k_btot(
    const int* __restrict__ binctr, int* __restrict__ bucket_base)
{
    __shared__ int tmp[256];
    const int t = threadIdx.x;
    int v = (t < NBUCK) ? binctr[t] : 0;
    tmp[t] = v;
    __syncthreads();
    #pragma unroll
    for (int off = 1; off < 256; off <<= 1) {
        int u = (t >= off) ? tmp[t - off] : 0;
        __syncthreads();
        tmp[t] += u;
        __syncthreads();
    }
    if (t < NBUCK) bucket_base[t] = tmp[t] - v;
}

// One block per bucket: counting-sort its 256 dst nodes in LDS, write
// contiguous csr_src slice + row_start for its nodes.
__global__ __launch_bounds__(1024) void k_sort(
    const int* __restrict__ stg,
    const int* __restrict__ binctr, const int* __restrict__ bucket_base,
    int* __restrict__ row_start, int* __restrict__ csr_src)
{
    __shared__ int cnt[256];
    __shared__ int off[256];
    const int b = blockIdx.x, t = threadIdx.x;
    const int n = binctr[b];
    const int sbase = b * CAP;
    const int obase = bucket_base[b];

    if (t < 256) cnt[t] = 0;
    __syncthreads();

    int mv[5], mk[5], mr[5];
    int c = 0;
    for (int i = t; i < n; i += 1024) {
        int v = stg[sbase + i];
        int k = v >> 16;                 // dst & 255
        mv[c] = v & 0xFFFF;              // src
        mk[c] = k;
        mr[c] = atomicAdd(&cnt[k], 1);
        ++c;
    }
    __syncthreads();

    if (t < 256) off[t] = cnt[t];
    __syncthreads();
    #pragma unroll
    for (int o = 1; o < 256; o <<= 1) {
        int u = (t < 256 && t >= o) ? off[t - o] : 0;
        __syncthreads();
        if (t < 256) off[t] += u;
        __syncthreads();
    }
    // off = inclusive scan; exclusive prefix = off[k] - cnt[k]

    if (t < 256) {
        int node = b * 256 + t;
        if (node < N_NODES) row_start[node] = obase + off[t] - cnt[t];
    }
    if (b == NBUCK - 1 && t == 0) row_start[N_NODES] = N_EDGES;

    for (int i = 0; i < c; ++i)
        csr_src[obase + off[mk[i]] - cnt[mk[i]] + mr[i]] = mv[i];
}

// ---------------------------------------------------------------------------
// GEMM1: h1 = x @ W1  (50000x128 @ 128x64) -> fp16 rows; fused ls1/ld1 (fp32).
__global__ __launch_bounds__(256) void k_gemm1(
    const float* __restrict__ x, const float* __restrict__ W1,
    const float* __restrict__ a_src, const float* __restrict__ a_dst,
    _Float16* __restrict__ h1h, float* __restrict__ ls, float* __restrict__ ld)
{
    __shared__ float As[64][128];   // 32 KB
    __shared__ float Bs[128][64];   // 32 KB
    const int tid = threadIdx.x;
    const int m0 = blockIdx.x * 64;

    {   // W1 (128x64 = 2048 float4) -> Bs
        const float4* Wv = (const float4*)W1;
        float4* Bv = (float4*)&Bs[0][0];
        #pragma unroll
        for (int i = 0; i < 8; ++i) Bv[tid + i * 256] = Wv[tid + i * 256];
    }
    {   // x tile (64x128) -> As, coalesced float4, zero-pad past N
        const float4* Xv = (const float4*)x;
        #pragma unroll
        for (int i = 0; i < 8; ++i) {
            int idx = tid + i * 256;
            int r = idx >> 5, kq = idx & 31;        // 32 float4 per row
            float4 v = make_float4(0.f, 0.f, 0.f, 0.f);
            if (m0 + r < N_NODES) v = Xv[(size_t)(m0 + r) * 32 + kq];
            ((float4*)&As[r][0])[kq] = v;
        }
    }
    __syncthreads();

    const int tx = tid & 15, ty = tid >> 4;
    const int c0 = tx * 4, r0 = ty * 4;
    float acc[4][4] = {};
    for (int k = 0; k < 128; k += 4) {
        float a_s[4][4];
        #pragma unroll
        for (int i = 0; i < 4; ++i) {
            float4 av = *(const float4*)&As[r0 + i][k];
            a_s[i][0] = av.x; a_s[i][1] = av.y; a_s[i][2] = av.z; a_s[i][3] = av.w;
        }
        #pragma unroll
        for (int kk = 0; kk < 4; ++kk) {
            float4 b = *(const float4*)&Bs[k + kk][c0];
            #pragma unroll
            for (int i = 0; i < 4; ++i) {
                acc[i][0] += a_s[i][kk] * b.x;
                acc[i][1] += a_s[i][kk] * b.y;
                acc[i][2] += a_s[i][kk] * b.z;
                acc[i][3] += a_s[i][kk] * b.w;
            }
        }
    }

    float as4[4], ad4[4];
    #pragma unroll
    for (int j = 0; j < 4; ++j) { as4[j] = a_src[c0 + j]; ad4[j] = a_dst[c0 + j]; }

    #pragma unroll
    for (int i = 0; i < 4; ++i) {
        int row = m0 + r0 + i;
        float pls = acc[i][0]*as4[0] + acc[i][1]*as4[1] + acc[i][2]*as4[2] + acc[i][3]*as4[3];
        float pld = acc[i][0]*ad4[0] + acc[i][1]*ad4[1] + acc[i][2]*ad4[2] + acc[i][3]*ad4[3];
        #pragma unroll
        for (int off = 1; off < 16; off <<= 1) {
            pls += __shfl_xor(pls, off, 64);
            pld += __shfl_xor(pld, off, 64);
        }
        if (row < N_NODES) {
            half4 hv;
            hv.x = (_Float16)acc[i][0]; hv.y = (_Float16)acc[i][1];
            hv.z = (_Float16)acc[i][2]; hv.w = (_Float16)acc[i][3];
            ((half4*)&h1h[(size_t)row * 64])[tx] = hv;
            if (tx == 0) { ls[row] = pls; ld[row] = pld; }
        }
    }
}

// ---------------------------------------------------------------------------
// Aggregate layer 1 (C=64): one wave per dst node.
// Lane = (eslot = lane>>4, c4 = lane&15): 16 lanes gather a row as half4
// (8 B each, 128 B/row), 4 slots process 4 different edges concurrently.
__global__ __launch_bounds__(256) void k_agg1(
    const int* __restrict__ csr_src, const int* __restrict__ row_start,
    const float* __restrict__ ls, const float* __restrict__ ld,
    const _Float16* __restrict__ h1h, const float* __restrict__ b1,
    float* __restrict__ acc1)
{
    const int node = blockIdx.x * 4 + (threadIdx.x >> 6);  // 12500*4 == N_NODES
    const int lane = threadIdx.x & 63;
    const int c4 = lane & 15, eslot = lane >> 4;
    const int beg = row_start[node], end = row_start[node + 1];
    const float ldv = ld[node];
    const half4* H = (const half4*)h1h;

    float4 acc = make_float4(0.f, 0.f, 0.f, 0.f);
    float sw = 0.f;
    for (int base = beg; base < end; base += 64) {
        const int cnt = min(64, end - base);
        int s = 0;
        float w = 0.f;
        if (lane < cnt) {
            s = csr_src[base + lane];              // coalesced
            float l = ls[s] + ldv;                 // one exp per EDGE
            l = l > 0.f ? l : SLOPE * l;
            w = __expf(l);
        }
        float wsum = w;                            // denominator via butterfly
        #pragma unroll
        for (int off = 1; off < 64; off <<= 1) wsum += __shfl_xor(wsum, off, 64);
        sw += wsum;

        int j = 0;                                 // 8 edges per iter (2/slot)
        for (; j + 8 <= cnt; j += 8) {
            int   s0 = __shfl(s, j + eslot, 64);
            int   s1 = __shfl(s, j + 4 + eslot, 64);
            float w0 = __shfl(w, j + eslot, 64);
            float w1 = __shfl(w, j + 4 + eslot, 64);
            half4 g0 = H[(size_t)s0 * 16 + c4];
            half4 g1 = H[(size_t)s1 * 16 + c4];
            acc.x += w0 * (float)g0.x; acc.y += w0 * (float)g0.y;
            acc.z += w0 * (float)g0.z; acc.w += w0 * (float)g0.w;
            acc.x += w1 * (float)g1.x; acc.y += w1 * (float)g1.y;
            acc.z += w1 * (float)g1.z; acc.w += w1 * (float)g1.w;
        }
        for (; j < cnt; j += 4) {                  // tail: invalid slots have w=0
            int   sj = __shfl(s, j + eslot, 64);
            float wj = __shfl(w, j + eslot, 64);
            half4 g = H[(size_t)sj * 16 + c4];
            acc.x += wj * (float)g.x; acc.y += wj * (float)g.y;
            acc.z += wj * (float)g.z; acc.w += wj * (float)g.w;
        }
    }
    // reduce across the 4 edge slots (xor bits 4,5)
    #pragma unroll
    for (int off = 16; off < 64; off <<= 1) {
        acc.x += __shfl_xor(acc.x, off, 64);
        acc.y += __shfl_xor(acc.y, off, 64);
        acc.z += __shfl_xor(acc.z, off, 64);
        acc.w += __shfl_xor(acc.w, off, 64);
    }
    if (eslot == 0) {
        float inv = sw > 0.f ? 1.f / sw : 0.f;
        float4 bb = ((const float4*)b1)[c4];
        ((float4*)&acc1[(size_t)node * 64])[c4] =
            make_float4(acc.x * inv + bb.x, acc.y * inv + bb.y,
                        acc.z * inv + bb.z, acc.w * inv + bb.w);
    }
}

// ---------------------------------------------------------------------------
// Epilogue layer1 + GEMM2: h2 = relu(acc1) @ W2 -> fp16 rows; fused ls2/ld2.
__global__ __launch_bounds__(256) void k_epi1(
    const float* __restrict__ acc1, const float* __restrict__ W2,
    const float* __restrict__ a_src2, const float* __restrict__ a_dst2,
    _Float16* __restrict__ h2h, float* __restrict__ ls2, float* __restrict__ ld2)
{
    __shared__ float Hs[64][68];
    __shared__ float W2s[64][32];
    const int tid = threadIdx.x;
    const int n0 = blockIdx.x * 64;

    {   // W2 (64x32 = 512 float4) -> LDS
        const float4* Wv = (const float4*)W2;
        float4* Ws = (float4*)&W2s[0][0];
        Ws[tid] = Wv[tid];
        Ws[tid + 256] = Wv[tid + 256];
    }
    {   // relu(acc1 rows) -> Hs, coalesced
        const float4* Av = (const float4*)acc1;
        #pragma unroll
        for (int i = 0; i < 4; ++i) {
            int idx = tid + i * 256;
            int r = idx >> 4, kq = idx & 15;
            float4 v = make_float4(0.f, 0.f, 0.f, 0.f);
            if (n0 + r < N_NODES) {
                v = Av[(size_t)(n0 + r) * 16 + kq];
                v.x = fmaxf(v.x, 0.f); v.y = fmaxf(v.y, 0.f);
                v.z = fmaxf(v.z, 0.f); v.w = fmaxf(v.w, 0.f);
            }
            ((float4*)&Hs[r][0])[kq] = v;
        }
    }
    __syncthreads();

    const int nl = tid >> 2, cg = tid & 3, c0 = cg * 8;
    float acc[8] = {};
    for (int k4 = 0; k4 < 16; ++k4) {
        float4 hv4 = *(const float4*)&Hs[nl][k4 * 4];
        #pragma unroll
        for (int kk = 0; kk < 4; ++kk) {
            float hv = kk == 0 ? hv4.x : kk == 1 ? hv4.y : kk == 2 ? hv4.z : hv4.w;
            int k = k4 * 4 + kk;
            float4 w0 = *(const float4*)&W2s[k][c0];
            float4 w1 = *(const float4*)&W2s[k][c0 + 4];
            acc[0] += hv * w0.x; acc[1] += hv * w0.y;
            acc[2] += hv * w0.z; acc[3] += hv * w0.w;
            acc[4] += hv * w1.x; acc[5] += hv * w1.y;
            acc[6] += hv * w1.z; acc[7] += hv * w1.w;
        }
    }

    float pls = 0.f, pld = 0.f;
    #pragma unroll
    for (int j = 0; j < 8; ++j) {
        pls += acc[j] * a_src2[c0 + j];
        pld += acc[j] * a_dst2[c0 + j];
    }
    pls += __shfl_xor(pls, 1, 64); pls += __shfl_xor(pls, 2, 64);
    pld += __shfl_xor(pld, 1, 64); pld += __shfl_xor(pld, 2, 64);

    int node = n0 + nl;
    if (node < N_NODES) {
        half4 lo, hi;
        lo.x = (_Float16)acc[0]; lo.y = (_Float16)acc[1];
        lo.z = (_Float16)acc[2]; lo.w = (_Float16)acc[3];
        hi.x = (_Float16)acc[4]; hi.y = (_Float16)acc[5];
        hi.z = (_Float16)acc[6]; hi.w = (_Float16)acc[7];
        ((half4*)&h2h[(size_t)node * 32])[cg * 2]     = lo;
        ((half4*)&h2h[(size_t)node * 32])[cg * 2 + 1] = hi;
        if (cg == 0) { ls2[node] = pls; ld2[node] = pld; }
    }
}

// ---------------------------------------------------------------------------
// Aggregate layer 2 (C=32): one 32-lane group per dst node.
// c4 = grp&7 (8 half4 channel groups, 64 B/row), eslot = grp>>3 (4 slots).
__global__ __launch_bounds__(256) void k_agg2(
    const int* __restrict__ csr_src, const int* __restrict__ row_start,
    const float* __restrict__ ls, const float* __restrict__ ld,
    const _Float16* __restrict__ h2h, const float* __restrict__ b2,
    float* __restrict__ out)
{
    const int idx = blockIdx.x * 256 + threadIdx.x;   // 6250*256 == N*32
    const int node = idx >> 5;
    const int grp = idx & 31;
    const int c4 = grp & 7, eslot = grp >> 3;
    const int beg = row_start[node], end = row_start[node + 1];
    const float ldv = ld[node];
    const half4* H = (const half4*)h2h;

    float4 acc = make_float4(0.f, 0.f, 0.f, 0.f);
    float sw = 0.f;
    for (int base = beg; base < end; base += 32) {
        const int cnt = min(32, end - base);
        int s = 0;
        float w = 0.f;
        if (grp < cnt) {
            s = csr_src[base + grp];
            float l = ls[s] + ldv;
            l = l > 0.f ? l : SLOPE * l;
            w = __expf(l);
        }
        float wsum = w;
        #pragma unroll
        for (int off = 1; off < 32; off <<= 1) wsum += __shfl_xor(wsum, off, 32);
        sw += wsum;

        int j = 0;
        for (; j + 8 <= cnt; j += 8) {
            int   s0 = __shfl(s, j + eslot, 32);
            int   s1 = __shfl(s, j + 4 + eslot, 32);
            float w0 = __shfl(w, j + eslot, 32);
            float w1 = __shfl(w, j + 4 + eslot, 32);
            half4 g0 = H[(size_t)s0 * 8 + c4];
            half4 g1 = H[(size_t)s1 * 8 + c4];
            acc.x += w0 * (float)g0.x; acc.y += w0 * (float)g0.y;
            acc.z += w0 * (float)g0.z; acc.w += w0 * (float)g0.w;
            acc.x += w1 * (float)g1.x; acc.y += w1 * (float)g1.y;
            acc.z += w1 * (float)g1.z; acc.w += w1 * (float)g1.w;
        }
        for (; j < cnt; j += 4) {
            int   sj = __shfl(s, j + eslot, 32);
            float wj = __shfl(w, j + eslot, 32);
            half4 g = H[(size_t)sj * 8 + c4];
            acc.x += wj * (float)g.x; acc.y += wj * (float)g.y;
            acc.z += wj * (float)g.z; acc.w += wj * (float)g.w;
        }
    }
    // reduce across the 4 edge slots (xor bits 3,4 of grp)
    #pragma unroll
    for (int off = 8; off < 32; off <<= 1) {
        acc.x += __shfl_xor(acc.x, off, 32);
        acc.y += __shfl_xor(acc.y, off, 32);
        acc.z += __shfl_xor(acc.z, off, 32);
        acc.w += __shfl_xor(acc.w, off, 32);
    }
    if (eslot == 0) {
        float inv = sw > 0.f ? 1.f / sw : 0.f;
        float4 bb = ((const float4*)b2)[c4];
        ((float4*)&out[(size_t)node * 32])[c4] =
            make_float4(acc.x * inv + bb.x, acc.y * inv + bb.y,
                        acc.z * inv + bb.z, acc.w * inv + bb.w);
    }
}

// ---------------------------------------------------------------------------
extern "C" void kernel_launch(void* const* d_in, const int* in_sizes, int n_in,
                              void* d_out, int out_size, void* d_ws, size_t ws_size,
                              hipStream_t stream)
{
    const float* x      = (const float*)d_in[0];
    const int*   ei     = (const int*)  d_in[1];
    const float* W1     = (const float*)d_in[2];
    const float* a_src1 = (const float*)d_in[3];
    const float* a_dst1 = (const float*)d_in[4];
    const float* b1     = (const float*)d_in[5];
    const float* W2     = (const float*)d_in[6];
    const float* a_src2 = (const float*)d_in[7];
    const float* a_dst2 = (const float*)d_in[8];
    const float* b2     = (const float*)d_in[9];
    const int* src = ei;
    const int* dst = ei + N_EDGES;
    float* out = (float*)d_out;

    // workspace layout (4B words), total ~5.75M words = 23 MB.
    // h1h (fp16, 1.6M words) holds 50000x64 halfs; stg (903,168 i) aliases it
    // (CSR build fully precedes k_gemm1 on the stream). h2h aliases h1h too
    // (50000x32 halfs = 0.8M words).
    float* ws   = (float*)d_ws;
    _Float16* h1h = (_Float16*)ws;           // words 0 .. 1,600,000
    float* acc1 = ws + 1600000;              // 3,200,000 f
    float* ls1  = ws + 4800000;              // 50,000 f
    float* ld1  = ws + 4850000;              // 50,000 f
    int* row_start   = (int*)(ws + 4900000); // 50,001 i (pad to 50,016)
    int* csr_src     = (int*)(ws + 4950016); // 800,000 i
    int* binctr      = (int*)(ws + 5750016); // 196 i (pad 256)
    int* bucket_base = (int*)(ws + 5750272); // 196 i (pad 256)
    int* stg = (int*)ws;                     // aliases h1h region
    _Float16* h2h = h1h;
    float* ls2 = ls1;
    float* ld2 = ld1;

    // CSR build (dst-sorted, reused by both layers)
    k_zerobins<<<1,   256,  0, stream>>>(binctr);
    k_bin     <<<98,  1024, 0, stream>>>(src, dst, binctr, stg);
    k_btot    <<<1,   256,  0, stream>>>(binctr, bucket_base);
    k_sort    <<<NBUCK, 1024, 0, stream>>>(stg, binctr, bucket_base,
                                           row_start, csr_src);

    // layer 1
    k_gemm1<<<782,   256, 0, stream>>>(x, W1, a_src1, a_dst1, h1h, ls1, ld1);
    k_agg1 <<<12500, 256, 0, stream>>>(csr_src, row_start, ls1, ld1, h1h, b1, acc1);

    // layer 2
    k_epi1 <<<782,  256, 0, stream>>>(acc1, W2, a_src2, a_dst2, h2h, ls2, ld2);
    k_agg2 <<<6250, 256, 0, stream>>>(csr_src, row_start, ls2, ld2, h2h, b2, out);
}